// Round 20
// baseline (238.580 us; speedup 1.0000x reference)
//
#include <hip/hip_runtime.h>
#include <hip/hip_bf16.h>
#include <math.h>

#define N_NODES 50000
#define N_EDGES 1600000
#define TE 64
#define LOG2E 1.44269504088896340736f
#define NBK 196            // dst buckets: bucket = dst >> 8 (256 nodes each)
#define BIN_CHUNK 8192
#define BIN_GRID ((N_EDGES + BIN_CHUNK - 1) / BIN_CHUNK)   // 196

typedef int vint2 __attribute__((ext_vector_type(2)));
typedef int vint4 __attribute__((ext_vector_type(4)));
typedef float vfloat4 __attribute__((ext_vector_type(4)));
typedef unsigned int uint;

__device__ __forceinline__ unsigned short f2bf(float f) {
    uint u = __float_as_uint(f);
    return (unsigned short)((u + 0x7fffu + ((u >> 16) & 1u)) >> 16);   // RNE
}
__device__ __forceinline__ float bf_lo(uint u) { return __uint_as_float(u << 16); }
__device__ __forceinline__ float bf_hi(uint u) { return __uint_as_float(u & 0xffff0000u); }

// ---------------- node transform ----------------
// h = concat(x, cos(t*omega+phase)) @ W, register-tiled GEMM (thread tile
// 4 nodes x 4 cols). T14 async-stage split + LDS double-buffer: per chunk,
// next chunk's W/x global loads are issued into REGISTERS before compute,
// and written to the other LDS buffer after compute (one barrier/chunk) --
// HBM/L2 latency hides under the ~1.8K-cycle FMA phase. te=cos(...) lives
// in a dedicated teS table computed once in the prologue.
// FINAL=0: h stored bf16 + s_src/s_dst. FINAL=1: only hw[n,h]=h·Whead and
// s_src needed (head projection commutes with the alpha-weighted sum);
// writes interleaved l1tab[n]={s0,hw0,...} + s_dst; skips hfeat16.
template<int IN_DIM, int FINAL>
__global__ __launch_bounds__(256) void transform_kernel(
    const float* __restrict__ xin, const float* __restrict__ tim,
    const float* __restrict__ omega, const float* __restrict__ phase,
    const float* __restrict__ W, const float* __restrict__ asrc,
    const float* __restrict__ adst, const float* __restrict__ whead,
    unsigned short* __restrict__ hfeat16,
    float* __restrict__ s_src, float* __restrict__ s_dst,
    float* __restrict__ l1tab)
{
    constexpr int K = IN_DIM + TE;
    constexpr int KC = 32;             // k-chunk
    constexpr int NCH = K / KC;
    constexpr int NXCH = IN_DIM / KC;  // xin chunks (te chunks follow)
    constexpr int BN = 64;             // nodes per block
    __shared__ float aS[2][KC][68];    // double-buffered xin chunk (transposed)
    __shared__ float wS[2][KC][64];    // double-buffered W chunk
    __shared__ float teS[TE][68];      // te table [dim][node], computed once
    __shared__ float tS[BN];

    const int tid = threadIdx.x;
    const int base = blockIdx.x * BN;

    if (tid < BN) {
        int n = base + tid;
        tS[tid] = (n < N_NODES) ? tim[n] : 0.f;
    }
    __syncthreads();

    // prologue A: te table (16 cosf/thread; omega/phase broadcast loads)
    #pragma unroll
    for (int j = 0; j < 16; ++j) {
        int idx = tid + j * 256;
        int kk = idx >> 6, nl = idx & 63;
        teS[kk][nl] = cosf(tS[nl] * omega[kk] + phase[kk]);
    }
    // prologue B: stage chunk 0 (always an xin chunk; IN_DIM >= 64)
    #pragma unroll
    for (int j = 0; j < 2; ++j) {
        int idx = tid + j * 256;
        int kk = idx >> 4, c4 = idx & 15;
        *(float4*)&wS[0][kk][c4 * 4] = ((const float4*)(W + (size_t)kk * 64))[c4];
    }
    #pragma unroll
    for (int j = 0; j < 2; ++j) {
        int idx = tid + j * 256;
        int nl = idx >> 3, kk = (idx & 7) * 4;
        int n = base + nl;
        float4 v = (n < N_NODES)
            ? ((const float4*)(xin + (size_t)n * IN_DIM))[idx & 7]
            : make_float4(0.f, 0.f, 0.f, 0.f);
        aS[0][kk + 0][nl] = v.x; aS[0][kk + 1][nl] = v.y;
        aS[0][kk + 2][nl] = v.z; aS[0][kk + 3][nl] = v.w;
    }
    __syncthreads();

    const int ty = tid >> 4;           // node quad
    const int tx = tid & 15;           // col quad
    float acc[4][4] = {};

    #pragma unroll
    for (int ch = 0; ch < NCH; ++ch) {
        const int cur = ch & 1, nxt = cur ^ 1;
        const int kg1 = (ch + 1) * KC;
        constexpr float4 f0 = {0.f, 0.f, 0.f, 0.f};
        float4 wr0 = f0, wr1 = f0, ar0 = f0, ar1 = f0;
        const bool have_next = (ch + 1 < NCH);
        const bool next_x = (kg1 < IN_DIM);

        // phase A: issue next chunk's global loads into registers
        if (have_next) {
            { int kk = tid >> 4, c4 = tid & 15;
              wr0 = ((const float4*)(W + (size_t)(kg1 + kk) * 64))[c4]; }
            { int idx = tid + 256; int kk = idx >> 4, c4 = idx & 15;
              wr1 = ((const float4*)(W + (size_t)(kg1 + kk) * 64))[c4]; }
            if (next_x) {
                { int nl = tid >> 3; int n = base + nl;
                  if (n < N_NODES)
                      ar0 = ((const float4*)(xin + (size_t)n * IN_DIM + kg1))[tid & 7]; }
                { int idx = tid + 256; int nl = idx >> 3; int n = base + nl;
                  if (n < N_NODES)
                      ar1 = ((const float4*)(xin + (size_t)n * IN_DIM + kg1))[idx & 7]; }
            }
        }

        // phase B: compute current chunk (xin chunks from aS, te from teS)
        const float (*ap)[68] = (ch < NXCH)
            ? (const float(*)[68])aS[cur]
            : (const float(*)[68])&teS[(ch - NXCH) * KC];
        #pragma unroll
        for (int k = 0; k < KC; ++k) {
            const float4 av = *(const float4*)&ap[k][ty * 4];
            const float4 wv = *(const float4*)&wS[cur][k][tx * 4];
            acc[0][0] = fmaf(av.x, wv.x, acc[0][0]);
            acc[0][1] = fmaf(av.x, wv.y, acc[0][1]);
            acc[0][2] = fmaf(av.x, wv.z, acc[0][2]);
            acc[0][3] = fmaf(av.x, wv.w, acc[0][3]);
            acc[1][0] = fmaf(av.y, wv.x, acc[1][0]);
            acc[1][1] = fmaf(av.y, wv.y, acc[1][1]);
            acc[1][2] = fmaf(av.y, wv.z, acc[1][2]);
            acc[1][3] = fmaf(av.y, wv.w, acc[1][3]);
            acc[2][0] = fmaf(av.z, wv.x, acc[2][0]);
            acc[2][1] = fmaf(av.z, wv.y, acc[2][1]);
            acc[2][2] = fmaf(av.z, wv.z, acc[2][2]);
            acc[2][3] = fmaf(av.z, wv.w, acc[2][3]);
            acc[3][0] = fmaf(av.w, wv.x, acc[3][0]);
            acc[3][1] = fmaf(av.w, wv.y, acc[3][1]);
            acc[3][2] = fmaf(av.w, wv.z, acc[3][2]);
            acc[3][3] = fmaf(av.w, wv.w, acc[3][3]);
        }

        // phase C: write staged registers to the other buffer
        if (have_next) {
            { int kk = tid >> 4, c4 = tid & 15;
              *(float4*)&wS[nxt][kk][c4 * 4] = wr0; }
            { int idx = tid + 256; int kk = idx >> 4, c4 = idx & 15;
              *(float4*)&wS[nxt][kk][c4 * 4] = wr1; }
            if (next_x) {
                { int nl = tid >> 3, kk = (tid & 7) * 4;
                  aS[nxt][kk + 0][nl] = ar0.x; aS[nxt][kk + 1][nl] = ar0.y;
                  aS[nxt][kk + 2][nl] = ar0.z; aS[nxt][kk + 3][nl] = ar0.w; }
                { int idx = tid + 256; int nl = idx >> 3, kk = (idx & 7) * 4;
                  aS[nxt][kk + 0][nl] = ar1.x; aS[nxt][kk + 1][nl] = ar1.y;
                  aS[nxt][kk + 2][nl] = ar1.z; aS[nxt][kk + 3][nl] = ar1.w; }
            }
        }
        __syncthreads();
    }

    // epilogue: per-head scores (+ hw head-dot if FINAL; else bf16 h stores)
    const float4 as = ((const float4*)asrc)[tx];
    const float4 ad = ((const float4*)adst)[tx];
    float4 wh = make_float4(0.f, 0.f, 0.f, 0.f);
    if (FINAL) wh = ((const float4*)whead)[tx];
    #pragma unroll
    for (int j = 0; j < 4; ++j) {
        const int n = base + ty * 4 + j;
        if (!FINAL && n < N_NODES) {
            ushort4 o;
            o.x = f2bf(acc[j][0]); o.y = f2bf(acc[j][1]);
            o.z = f2bf(acc[j][2]); o.w = f2bf(acc[j][3]);
            *(ushort4*)(hfeat16 + (size_t)n * 64 + tx * 4) = o;
        }
        float vs = acc[j][0] * as.x + acc[j][1] * as.y
                 + acc[j][2] * as.z + acc[j][3] * as.w;
        float vd = acc[j][0] * ad.x + acc[j][1] * ad.y
                 + acc[j][2] * ad.z + acc[j][3] * ad.w;
        float vw = 0.f;
        if (FINAL)
            vw = acc[j][0] * wh.x + acc[j][1] * wh.y
               + acc[j][2] * wh.z + acc[j][3] * wh.w;
        vs += __shfl_xor(vs, 1, 64); vs += __shfl_xor(vs, 2, 64);
        vd += __shfl_xor(vd, 1, 64); vd += __shfl_xor(vd, 2, 64);
        if (FINAL) { vw += __shfl_xor(vw, 1, 64); vw += __shfl_xor(vw, 2, 64); }
        if ((tx & 3) == 0 && n < N_NODES) {
            if (FINAL) {
                const int hh = tx >> 2;
                l1tab[(size_t)n * 8 + hh * 2]     = vs * LOG2E;
                l1tab[(size_t)n * 8 + hh * 2 + 1] = vw;
                s_dst[n * 4 + hh] = vd * LOG2E;
            } else {
                s_src[n * 4 + (tx >> 2)] = vs * LOG2E;   // exp2 domain
                s_dst[n * 4 + (tx >> 2)] = vd * LOG2E;
            }
        }
    }
}

// ---------------- CSR build: count-matrix two-level bucket sort ----------
// Bucket = dst>>8. All random writes confined to single-block windows ->
// structural write merging. cmat[chunk][bucket] counts let bin run
// single-pass with zero global atomics.

__global__ __launch_bounds__(256) void count_kernel(
    const int* __restrict__ dst, int* __restrict__ cmat)
{
    __shared__ int c[NBK];
    for (int t = threadIdx.x; t < NBK; t += 256) c[t] = 0;
    __syncthreads();
    const int b4 = blockIdx.x * (BIN_CHUNK / 4);
    const int e4n = N_EDGES / 4;       // E % 4 == 0
    const vint4* d4p = (const vint4*)dst;
    #pragma unroll
    for (int q = 0; q < BIN_CHUNK / 4 / 256; ++q) {
        int i4 = b4 + q * 256 + threadIdx.x;
        if (i4 < e4n) {
            vint4 d4 = __builtin_nontemporal_load(d4p + i4);
            atomicAdd(&c[d4.x >> 8], 1);
            atomicAdd(&c[d4.y >> 8], 1);
            atomicAdd(&c[d4.z >> 8], 1);
            atomicAdd(&c[d4.w >> 8], 1);
        }
    }
    __syncthreads();
    for (int t = threadIdx.x; t < NBK; t += 256)
        cmat[blockIdx.x * NBK + t] = c[t];
}

__global__ __launch_bounds__(256) void cscan_kernel(
    int* __restrict__ cmat, int* __restrict__ bstart)
{
    __shared__ int s[256];
    const int t = threadIdx.x;
    int run = 0;
    if (t < NBK) {
        #pragma unroll 8
        for (int c = 0; c < BIN_GRID; ++c) {
            int v = cmat[c * NBK + t];
            cmat[c * NBK + t] = run;
            run += v;
        }
    }
    s[t] = (t < NBK) ? run : 0;
    const int own = s[t];
    __syncthreads();
    #pragma unroll
    for (int off = 1; off < 256; off <<= 1) {
        int u = (t >= off) ? s[t - off] : 0;
        __syncthreads();
        s[t] += u;
        __syncthreads();
    }
    if (t < NBK) bstart[t] = s[t] - own;
    if (t == NBK - 1) bstart[NBK] = s[t];
}

__global__ __launch_bounds__(256) void bin_kernel(
    const int* __restrict__ dst, const int* __restrict__ src,
    const float* __restrict__ ew,
    const int* __restrict__ cmat, const int* __restrict__ bstart,
    int* __restrict__ rdst, int2* __restrict__ rpair)
{
    __shared__ int gb[NBK];
    __shared__ int cnt[NBK];
    const int tid = threadIdx.x;
    for (int t = tid; t < NBK; t += 256) {
        gb[t] = cmat[blockIdx.x * NBK + t] + bstart[t];
        cnt[t] = 0;
    }
    __syncthreads();

    const int b4 = blockIdx.x * (BIN_CHUNK / 4);
    const int e4n = N_EDGES / 4;       // E % 4 == 0
    const vint4* d4p = (const vint4*)dst;
    const vint4* s4p = (const vint4*)src;
    const vfloat4* w4p = (const vfloat4*)ew;

    #pragma unroll
    for (int q = 0; q < BIN_CHUNK / 4 / 256; ++q) {
        int i4 = b4 + q * 256 + tid;
        if (i4 < e4n) {
            vint4 d4 = __builtin_nontemporal_load(d4p + i4);
            vint4 s4 = __builtin_nontemporal_load(s4p + i4);
            vfloat4 w4 = __builtin_nontemporal_load(w4p + i4);
            #pragma unroll
            for (int j = 0; j < 4; ++j) {
                const int d = j == 0 ? d4.x : j == 1 ? d4.y : j == 2 ? d4.z : d4.w;
                const int s = j == 0 ? s4.x : j == 1 ? s4.y : j == 2 ? s4.z : s4.w;
                const float w = j == 0 ? w4.x : j == 1 ? w4.y : j == 2 ? w4.z : w4.w;
                const int bk = d >> 8;
                const int r = atomicAdd(&cnt[bk], 1);
                const int pos = gb[bk] + r;
                rdst[pos] = d;
                rpair[pos] = make_int2(s, __float_as_int(w));
            }
        }
    }
}

__global__ __launch_bounds__(256) void place_kernel(
    const int* __restrict__ bstart, const int* __restrict__ rdst,
    const int2* __restrict__ rpair,
    int* __restrict__ deg, int* __restrict__ rowptr, int2* __restrict__ epair)
{
    __shared__ int ldeg[256];
    __shared__ int ls[256];
    __shared__ int lcur[256];
    const int t = threadIdx.x;
    const int b = blockIdx.x;
    const int lo = bstart[b], hi = bstart[b + 1];
    const int nbase = b << 8;

    ldeg[t] = 0;
    __syncthreads();
    for (int i = lo + t; i < hi; i += 256)
        atomicAdd(&ldeg[rdst[i] & 255], 1);
    __syncthreads();

    const int v = ldeg[t];
    ls[t] = v;
    __syncthreads();
    #pragma unroll
    for (int off = 1; off < 256; off <<= 1) {
        int u = (t >= off) ? ls[t - off] : 0;
        __syncthreads();
        ls[t] += u;
        __syncthreads();
    }
    const int excl = ls[t] - v + lo;
    const int n = nbase + t;
    if (n < N_NODES) { rowptr[n] = excl; deg[n] = v; }
    lcur[t] = excl;
    __syncthreads();

    const vint2* rpv = (const vint2*)rpair;
    for (int i = lo + t; i < hi; i += 256) {
        const int d = rdst[i];
        vint2 rp = __builtin_nontemporal_load(rpv + i);
        const int pos = atomicAdd(&lcur[d & 255], 1);
        epair[pos] = make_int2(rp.x, rp.y);
    }
}

// ---------------- layer-0 aggregation (full 64-dim output) ----------------
// one wave per node; 8 subgroups x 8 lanes; UNROLL-BY-4: 4 independent
// gather chains per lane (real VALU work is ~12% of runtime -> latency/MLP
// bound; unroll-2 gave +15%, double again). ~57 VGPR stays in the <=64
// occupancy tier. w=0 zero-fill keeps the tail guard-free.
__global__ __launch_bounds__(256) void aggregate_kernel(
    const int* __restrict__ rowptr, const int* __restrict__ deg,
    const int2* __restrict__ epair,
    const float* __restrict__ s_src, const float* __restrict__ s_dst,
    const unsigned short* __restrict__ hfeat16,
    float* __restrict__ outp)
{
    const int n = blockIdx.x * 4 + (threadIdx.x >> 6);
    if (n >= N_NODES) return;
    const int lane = threadIdx.x & 63;
    const int g = lane >> 3;          // subgroup (edge slot 0..7)
    const int sl = lane & 7;          // feature octet
    const int hh = sl >> 1;           // head of my features
    const float sdst = s_dst[n * 4 + hh];
    const int beg = rowptr[n];
    const int cnt = deg[n];
    const vint2* epv = (const vint2*)epair + beg;
    const vint2 zz = {0, 0};

    float den = 0.f;
    float4 a0 = make_float4(0.f, 0.f, 0.f, 0.f);
    float4 a1 = make_float4(0.f, 0.f, 0.f, 0.f);

    int i = g;
    vint2 ep0 = (i      < cnt) ? __builtin_nontemporal_load(epv + i)      : zz;
    vint2 ep1 = (i + 8  < cnt) ? __builtin_nontemporal_load(epv + i + 8)  : zz;
    vint2 ep2 = (i + 16 < cnt) ? __builtin_nontemporal_load(epv + i + 16) : zz;
    vint2 ep3 = (i + 24 < cnt) ? __builtin_nontemporal_load(epv + i + 24) : zz;
    while (i < cnt) {
        const int s0 = ep0.x, s1 = ep1.x, s2 = ep2.x, s3 = ep3.x;
        const float w0 = __int_as_float(ep0.y);
        const float w1 = __int_as_float(ep1.y);
        const float w2 = __int_as_float(ep2.y);
        const float w3 = __int_as_float(ep3.y);
        const int in2 = i + 32;
        ep0 = (in2      < cnt) ? __builtin_nontemporal_load(epv + in2)      : zz;
        ep1 = (in2 + 8  < cnt) ? __builtin_nontemporal_load(epv + in2 + 8)  : zz;
        ep2 = (in2 + 16 < cnt) ? __builtin_nontemporal_load(epv + in2 + 16) : zz;
        ep3 = (in2 + 24 < cnt) ? __builtin_nontemporal_load(epv + in2 + 24) : zz;

        const float ss0 = s_src[(size_t)s0 * 4 + hh];
        const float ss1 = s_src[(size_t)s1 * 4 + hh];
        const float ss2 = s_src[(size_t)s2 * 4 + hh];
        const float ss3 = s_src[(size_t)s3 * 4 + hh];
        const uint4 hv0 = *(const uint4*)(hfeat16 + (size_t)s0 * 64 + sl * 8);
        const uint4 hv1 = *(const uint4*)(hfeat16 + (size_t)s1 * 64 + sl * 8);
        const uint4 hv2 = *(const uint4*)(hfeat16 + (size_t)s2 * 64 + sl * 8);
        const uint4 hv3 = *(const uint4*)(hfeat16 + (size_t)s3 * 64 + sl * 8);

        float sc0 = ss0 + sdst; sc0 = fmaxf(sc0, 0.2f * sc0);
        const float p0 = __builtin_amdgcn_exp2f(sc0) * w0;
        float sc1 = ss1 + sdst; sc1 = fmaxf(sc1, 0.2f * sc1);
        const float p1 = __builtin_amdgcn_exp2f(sc1) * w1;
        float sc2 = ss2 + sdst; sc2 = fmaxf(sc2, 0.2f * sc2);
        const float p2 = __builtin_amdgcn_exp2f(sc2) * w2;
        float sc3 = ss3 + sdst; sc3 = fmaxf(sc3, 0.2f * sc3);
        const float p3 = __builtin_amdgcn_exp2f(sc3) * w3;
        den += (p0 + p1) + (p2 + p3);

        a0.x = fmaf(p0, bf_lo(hv0.x), a0.x); a0.y = fmaf(p0, bf_hi(hv0.x), a0.y);
        a0.z = fmaf(p0, bf_lo(hv0.y), a0.z); a0.w = fmaf(p0, bf_hi(hv0.y), a0.w);
        a1.x = fmaf(p0, bf_lo(hv0.z), a1.x); a1.y = fmaf(p0, bf_hi(hv0.z), a1.y);
        a1.z = fmaf(p0, bf_lo(hv0.w), a1.z); a1.w = fmaf(p0, bf_hi(hv0.w), a1.w);
        a0.x = fmaf(p1, bf_lo(hv1.x), a0.x); a0.y = fmaf(p1, bf_hi(hv1.x), a0.y);
        a0.z = fmaf(p1, bf_lo(hv1.y), a0.z); a0.w = fmaf(p1, bf_hi(hv1.y), a0.w);
        a1.x = fmaf(p1, bf_lo(hv1.z), a1.x); a1.y = fmaf(p1, bf_hi(hv1.z), a1.y);
        a1.z = fmaf(p1, bf_lo(hv1.w), a1.z); a1.w = fmaf(p1, bf_hi(hv1.w), a1.w);
        a0.x = fmaf(p2, bf_lo(hv2.x), a0.x); a0.y = fmaf(p2, bf_hi(hv2.x), a0.y);
        a0.z = fmaf(p2, bf_lo(hv2.y), a0.z); a0.w = fmaf(p2, bf_hi(hv2.y), a0.w);
        a1.x = fmaf(p2, bf_lo(hv2.z), a1.x); a1.y = fmaf(p2, bf_hi(hv2.z), a1.y);
        a1.z = fmaf(p2, bf_lo(hv2.w), a1.z); a1.w = fmaf(p2, bf_hi(hv2.w), a1.w);
        a0.x = fmaf(p3, bf_lo(hv3.x), a0.x); a0.y = fmaf(p3, bf_hi(hv3.x), a0.y);
        a0.z = fmaf(p3, bf_lo(hv3.y), a0.z); a0.w = fmaf(p3, bf_hi(hv3.y), a0.w);
        a1.x = fmaf(p3, bf_lo(hv3.z), a1.x); a1.y = fmaf(p3, bf_hi(hv3.z), a1.y);
        a1.z = fmaf(p3, bf_lo(hv3.w), a1.z); a1.w = fmaf(p3, bf_hi(hv3.w), a1.w);

        i = in2;
    }

    // merge 8 subgroups (lane bits 3,4,5)
    #pragma unroll
    for (int off = 8; off <= 32; off <<= 1) {
        den  += __shfl_xor(den, off, 64);
        a0.x += __shfl_xor(a0.x, off, 64); a0.y += __shfl_xor(a0.y, off, 64);
        a0.z += __shfl_xor(a0.z, off, 64); a0.w += __shfl_xor(a0.w, off, 64);
        a1.x += __shfl_xor(a1.x, off, 64); a1.y += __shfl_xor(a1.y, off, 64);
        a1.z += __shfl_xor(a1.z, off, 64); a1.w += __shfl_xor(a1.w, off, 64);
    }

    const float inv = 1.f / (den + 1e-16f);
    if (g == 0) {
        float4 v0, v1;
        v0.x = a0.x * inv; v0.x = v0.x > 0.f ? v0.x : expm1f(v0.x);
        v0.y = a0.y * inv; v0.y = v0.y > 0.f ? v0.y : expm1f(v0.y);
        v0.z = a0.z * inv; v0.z = v0.z > 0.f ? v0.z : expm1f(v0.z);
        v0.w = a0.w * inv; v0.w = v0.w > 0.f ? v0.w : expm1f(v0.w);
        v1.x = a1.x * inv; v1.x = v1.x > 0.f ? v1.x : expm1f(v1.x);
        v1.y = a1.y * inv; v1.y = v1.y > 0.f ? v1.y : expm1f(v1.y);
        v1.z = a1.z * inv; v1.z = v1.z > 0.f ? v1.z : expm1f(v1.z);
        v1.w = a1.w * inv; v1.w = v1.w > 0.f ? v1.w : expm1f(v1.w);
        float4* op = (float4*)(outp + (size_t)n * 64 + sl * 8);
        op[0] = v0; op[1] = v1;
    }
}

// ---------------- layer-1 head-collapsed aggregation ----------------
// out[n] = sum_h (sum_e p_eh * hw[s_e,h]) / den_h + b. Per edge only one
// float2 {s,hw} gathered from the interleaved 32B l1tab record.
// one wave per node; 16 subgroups x 4 lanes; unroll-by-2.
__global__ __launch_bounds__(256) void head_aggregate_kernel(
    const int* __restrict__ rowptr, const int* __restrict__ deg,
    const int2* __restrict__ epair,
    const float* __restrict__ l1tab, const float* __restrict__ s_dst,
    const float* __restrict__ bhead, float* __restrict__ outp)
{
    const int n = blockIdx.x * 4 + (threadIdx.x >> 6);
    if (n >= N_NODES) return;
    const int lane = threadIdx.x & 63;
    const int g = lane >> 2;          // subgroup (edge slot 0..15)
    const int h = lane & 3;           // head
    const float sdst = s_dst[n * 4 + h];
    const int beg = rowptr[n];
    const int cnt = deg[n];
    const vint2* epv = (const vint2*)epair + beg;
    const vint2 zz = {0, 0};

    float den = 0.f, num = 0.f;

    int i = g;
    vint2 ep0 = (i < cnt) ? __builtin_nontemporal_load(epv + i) : zz;
    vint2 ep1 = (i + 16 < cnt) ? __builtin_nontemporal_load(epv + i + 16) : zz;
    while (i < cnt) {
        const int s0 = ep0.x, s1 = ep1.x;
        const float w0 = __int_as_float(ep0.y);
        const float w1 = __int_as_float(ep1.y);
        const float2 rec0 = *(const float2*)(l1tab + (size_t)s0 * 8 + h * 2);
        const float2 rec1 = *(const float2*)(l1tab + (size_t)s1 * 8 + h * 2);
        vint2 en0 = (i + 32 < cnt) ? __builtin_nontemporal_load(epv + i + 32) : zz;
        vint2 en1 = (i + 48 < cnt) ? __builtin_nontemporal_load(epv + i + 48) : zz;

        float sc0 = rec0.x + sdst;
        sc0 = fmaxf(sc0, 0.2f * sc0);                    // leaky relu (log2 domain)
        const float p0 = __builtin_amdgcn_exp2f(sc0) * w0;
        float sc1 = rec1.x + sdst;
        sc1 = fmaxf(sc1, 0.2f * sc1);
        const float p1 = __builtin_amdgcn_exp2f(sc1) * w1;
        den += p0 + p1;
        num = fmaf(p0, rec0.y, num);
        num = fmaf(p1, rec1.y, num);

        ep0 = en0; ep1 = en1; i += 32;
    }

    // merge 16 subgroups (lane bits 2..5)
    #pragma unroll
    for (int off = 4; off <= 32; off <<= 1) {
        den += __shfl_xor(den, off, 64);
        num += __shfl_xor(num, off, 64);
    }

    float v = num / (den + 1e-16f);
    v += __shfl_xor(v, 1, 64);
    v += __shfl_xor(v, 2, 64);
    if (lane == 0) outp[n] = v + bhead[0];
}

extern "C" void kernel_launch(void* const* d_in, const int* in_sizes, int n_in,
                              void* d_out, int out_size, void* d_ws, size_t ws_size,
                              hipStream_t stream) {
    const float* x      = (const float*)d_in[0];
    const int*   eidx   = (const int*)d_in[1];
    const float* ew     = (const float*)d_in[2];
    const float* tim    = (const float*)d_in[3];
    const float* omega0 = (const float*)d_in[4];
    const float* phase0 = (const float*)d_in[5];
    const float* W0     = (const float*)d_in[6];
    const float* asrc0  = (const float*)d_in[7];
    const float* adst0  = (const float*)d_in[8];
    const float* omega1 = (const float*)d_in[9];
    const float* phase1 = (const float*)d_in[10];
    const float* W1     = (const float*)d_in[11];
    const float* asrc1  = (const float*)d_in[12];
    const float* adst1  = (const float*)d_in[13];
    const float* Whead  = (const float*)d_in[14];
    const float* bhead  = (const float*)d_in[15];
    float* out = (float*)d_out;

    const int* src = eidx;
    const int* dst = eidx + N_EDGES;

    float* ws = (float*)d_ws;
    unsigned short* hfeat16 = (unsigned short*)ws;   // N*64 ushorts (6.4MB)
    float* x1    = (float*)(hfeat16 + (size_t)N_NODES * 64);  // N*64 floats
    float* s_src = x1    + (size_t)N_NODES * 64;     // N*4
    float* s_dst = s_src + (size_t)N_NODES * 4;      // N*4
    int2* epair  = (int2*)(s_dst + (size_t)N_NODES * 4);   // E int2
    int* deg     = (int*)(epair + (size_t)N_EDGES);  // N
    int* rowptr  = deg + N_NODES;                    // N
    int* bstart  = rowptr + N_NODES;                 // NBK+1
    int* cmat    = bstart + NBK + 1;                 // BIN_GRID*NBK (153KB)
    float* l1tab = (float*)(cmat + BIN_GRID * NBK);  // N*8 floats (1.6MB)
    // record arrays alias dead buffers: consumed by place() before their
    // aliases are written (hfeat16 by transform<128>, x1 by aggregate).
    int*  rdst  = (int*)hfeat16;                     // E ints
    int2* rpair = (int2*)x1;                         // E int2

    const int tf_grid  = (N_NODES + 63) / 64;        // 782
    const int agg_grid = (N_NODES + 3) / 4;

    // ---- CSR build (count-matrix bucket sort; shared by both layers) ----
    count_kernel<<<BIN_GRID, 256, 0, stream>>>(dst, cmat);
    cscan_kernel<<<1, 256, 0, stream>>>(cmat, bstart);
    bin_kernel<<<BIN_GRID, 256, 0, stream>>>(dst, src, ew, cmat, bstart, rdst, rpair);
    place_kernel<<<NBK, 256, 0, stream>>>(bstart, rdst, rpair, deg, rowptr, epair);

    // ---- layer 0 ----
    transform_kernel<128, 0><<<tf_grid, 256, 0, stream>>>(
        x, tim, omega0, phase0, W0, asrc0, adst0, Whead,
        hfeat16, s_src, s_dst, l1tab);
    aggregate_kernel<<<agg_grid, 256, 0, stream>>>(
        rowptr, deg, epair, s_src, s_dst, hfeat16, x1);

    // ---- layer 1 (head-collapsed: h@Whead folded into per-node hw) ----
    transform_kernel<64, 1><<<tf_grid, 256, 0, stream>>>(
        x1, tim, omega1, phase1, W1, asrc1, adst1, Whead,
        hfeat16, s_src, s_dst, l1tab);
    head_aggregate_kernel<<<agg_grid, 256, 0, stream>>>(
        rowptr, deg, epair, l1tab, s_dst, bhead, out);
}

// Round 21
// 211.497 us; speedup vs baseline: 1.1281x; 1.1281x over previous
//
#include <hip/hip_runtime.h>
#include <hip/hip_bf16.h>
#include <math.h>

#define N_NODES 50000
#define N_EDGES 1600000
#define TE 64
#define LOG2E 1.44269504088896340736f
#define NBK 196            // dst buckets: bucket = dst >> 8 (256 nodes each)
#define BIN_CHUNK 8192
#define BIN_GRID ((N_EDGES + BIN_CHUNK - 1) / BIN_CHUNK)   // 196

typedef int vint2 __attribute__((ext_vector_type(2)));
typedef int vint4 __attribute__((ext_vector_type(4)));
typedef float vfloat4 __attribute__((ext_vector_type(4)));
typedef unsigned int uint;

__device__ __forceinline__ unsigned short f2bf(float f) {
    uint u = __float_as_uint(f);
    return (unsigned short)((u + 0x7fffu + ((u >> 16) & 1u)) >> 16);   // RNE
}
__device__ __forceinline__ float bf_lo(uint u) { return __uint_as_float(u << 16); }
__device__ __forceinline__ float bf_hi(uint u) { return __uint_as_float(u & 0xffff0000u); }

// ---------------- node transform ----------------
// ROUND-18 PROVEN VERSION (41.6us, VGPR 76, 17.4KB LDS). Round-20's
// register-staged double-buffer variant blew VGPR to 256 -> occupancy 8.6%
// -> 74us: at 3 blocks/CU the transform needs occupancy, not in-wave
// pipelining. h = concat(x, cos(t*omega+phase)) @ W, register-tiled GEMM.
// FINAL=0: h stored bf16 + s_src/s_dst. FINAL=1: only hw[n,h]=h·Whead and
// s_src needed; writes interleaved l1tab[n]={s0,hw0,...} + s_dst.
template<int IN_DIM, int FINAL>
__global__ __launch_bounds__(256) void transform_kernel(
    const float* __restrict__ xin, const float* __restrict__ tim,
    const float* __restrict__ omega, const float* __restrict__ phase,
    const float* __restrict__ W, const float* __restrict__ asrc,
    const float* __restrict__ adst, const float* __restrict__ whead,
    unsigned short* __restrict__ hfeat16,
    float* __restrict__ s_src, float* __restrict__ s_dst,
    float* __restrict__ l1tab)
{
    constexpr int K = IN_DIM + TE;
    constexpr int KC = 32;             // k-chunk
    constexpr int NCH = K / KC;
    constexpr int BN = 64;             // nodes per block
    __shared__ float aS[KC][68];       // transposed a-chunk (padded row: 272B)
    __shared__ float wS[KC][64];
    __shared__ float tS[BN];

    const int tid = threadIdx.x;
    const int base = blockIdx.x * BN;

    if (tid < BN) {
        int n = base + tid;
        tS[tid] = (n < N_NODES) ? tim[n] : 0.f;
    }

    const int ty = tid >> 4;           // node quad: nodes ty*4 .. ty*4+3
    const int tx = tid & 15;           // col slot: cols tx*4 .. tx*4+3

    float acc[4][4] = {};

    for (int ch = 0; ch < NCH; ++ch) {
        const int kg0 = ch * KC;
        __syncthreads();               // previous chunk fully consumed

        // stage W chunk: 32x64 floats = 512 float4, 2 per thread (coalesced)
        #pragma unroll
        for (int j = 0; j < 2; ++j) {
            int idx = tid + j * 256;                    // float4 index
            int kk = idx >> 4, c4 = idx & 15;
            *(float4*)&wS[kk][c4 * 4] =
                ((const float4*)(W + (size_t)(kg0 + kk) * 64))[c4];
        }

        // stage a chunk (transposed)
        if (kg0 < IN_DIM) {
            #pragma unroll
            for (int j = 0; j < 2; ++j) {
                int idx = tid + j * 256;
                int nl = idx >> 3, kk = (idx & 7) * 4;
                int n = base + nl;
                float4 v = (n < N_NODES)
                    ? ((const float4*)(xin + (size_t)n * IN_DIM + kg0))[idx & 7]
                    : make_float4(0.f, 0.f, 0.f, 0.f);
                aS[kk + 0][nl] = v.x;
                aS[kk + 1][nl] = v.y;
                aS[kk + 2][nl] = v.z;
                aS[kk + 3][nl] = v.w;
            }
        } else {
            #pragma unroll
            for (int j = 0; j < 8; ++j) {
                int idx = tid + j * 256;
                int kk = idx >> 6, nl = idx & 63;
                int kg = kg0 + kk - IN_DIM;
                aS[kk][nl] = cosf(tS[nl] * omega[kg] + phase[kg]);
            }
        }
        __syncthreads();

        #pragma unroll
        for (int k = 0; k < KC; ++k) {
            const float4 av = *(const float4*)&aS[k][ty * 4];
            const float4 wv = *(const float4*)&wS[k][tx * 4];
            acc[0][0] = fmaf(av.x, wv.x, acc[0][0]);
            acc[0][1] = fmaf(av.x, wv.y, acc[0][1]);
            acc[0][2] = fmaf(av.x, wv.z, acc[0][2]);
            acc[0][3] = fmaf(av.x, wv.w, acc[0][3]);
            acc[1][0] = fmaf(av.y, wv.x, acc[1][0]);
            acc[1][1] = fmaf(av.y, wv.y, acc[1][1]);
            acc[1][2] = fmaf(av.y, wv.z, acc[1][2]);
            acc[1][3] = fmaf(av.y, wv.w, acc[1][3]);
            acc[2][0] = fmaf(av.z, wv.x, acc[2][0]);
            acc[2][1] = fmaf(av.z, wv.y, acc[2][1]);
            acc[2][2] = fmaf(av.z, wv.z, acc[2][2]);
            acc[2][3] = fmaf(av.z, wv.w, acc[2][3]);
            acc[3][0] = fmaf(av.w, wv.x, acc[3][0]);
            acc[3][1] = fmaf(av.w, wv.y, acc[3][1]);
            acc[3][2] = fmaf(av.w, wv.z, acc[3][2]);
            acc[3][3] = fmaf(av.w, wv.w, acc[3][3]);
        }
    }

    // epilogue: per-head scores (+ hw head-dot if FINAL; else bf16 h stores)
    const float4 as = ((const float4*)asrc)[tx];
    const float4 ad = ((const float4*)adst)[tx];
    float4 wh = make_float4(0.f, 0.f, 0.f, 0.f);
    if (FINAL) wh = ((const float4*)whead)[tx];
    #pragma unroll
    for (int j = 0; j < 4; ++j) {
        const int n = base + ty * 4 + j;
        if (!FINAL && n < N_NODES) {
            ushort4 o;
            o.x = f2bf(acc[j][0]); o.y = f2bf(acc[j][1]);
            o.z = f2bf(acc[j][2]); o.w = f2bf(acc[j][3]);
            *(ushort4*)(hfeat16 + (size_t)n * 64 + tx * 4) = o;
        }
        float vs = acc[j][0] * as.x + acc[j][1] * as.y
                 + acc[j][2] * as.z + acc[j][3] * as.w;
        float vd = acc[j][0] * ad.x + acc[j][1] * ad.y
                 + acc[j][2] * ad.z + acc[j][3] * ad.w;
        float vw = 0.f;
        if (FINAL)
            vw = acc[j][0] * wh.x + acc[j][1] * wh.y
               + acc[j][2] * wh.z + acc[j][3] * wh.w;
        vs += __shfl_xor(vs, 1, 64); vs += __shfl_xor(vs, 2, 64);
        vd += __shfl_xor(vd, 1, 64); vd += __shfl_xor(vd, 2, 64);
        if (FINAL) { vw += __shfl_xor(vw, 1, 64); vw += __shfl_xor(vw, 2, 64); }
        if ((tx & 3) == 0 && n < N_NODES) {
            if (FINAL) {
                const int hh = tx >> 2;
                l1tab[(size_t)n * 8 + hh * 2]     = vs * LOG2E;
                l1tab[(size_t)n * 8 + hh * 2 + 1] = vw;
                s_dst[n * 4 + hh] = vd * LOG2E;
            } else {
                s_src[n * 4 + (tx >> 2)] = vs * LOG2E;   // exp2 domain
                s_dst[n * 4 + (tx >> 2)] = vd * LOG2E;
            }
        }
    }
}

// ---------------- CSR build: count-matrix two-level bucket sort ----------
// Bucket = dst>>8. All random writes confined to single-block windows ->
// structural write merging. cmat[chunk][bucket] counts let bin run
// single-pass with zero global atomics.

__global__ __launch_bounds__(256) void count_kernel(
    const int* __restrict__ dst, int* __restrict__ cmat)
{
    __shared__ int c[NBK];
    for (int t = threadIdx.x; t < NBK; t += 256) c[t] = 0;
    __syncthreads();
    const int b4 = blockIdx.x * (BIN_CHUNK / 4);
    const int e4n = N_EDGES / 4;       // E % 4 == 0
    const vint4* d4p = (const vint4*)dst;
    #pragma unroll
    for (int q = 0; q < BIN_CHUNK / 4 / 256; ++q) {
        int i4 = b4 + q * 256 + threadIdx.x;
        if (i4 < e4n) {
            vint4 d4 = __builtin_nontemporal_load(d4p + i4);
            atomicAdd(&c[d4.x >> 8], 1);
            atomicAdd(&c[d4.y >> 8], 1);
            atomicAdd(&c[d4.z >> 8], 1);
            atomicAdd(&c[d4.w >> 8], 1);
        }
    }
    __syncthreads();
    for (int t = threadIdx.x; t < NBK; t += 256)
        cmat[blockIdx.x * NBK + t] = c[t];
}

__global__ __launch_bounds__(256) void cscan_kernel(
    int* __restrict__ cmat, int* __restrict__ bstart)
{
    __shared__ int s[256];
    const int t = threadIdx.x;
    int run = 0;
    if (t < NBK) {
        #pragma unroll 8
        for (int c = 0; c < BIN_GRID; ++c) {
            int v = cmat[c * NBK + t];
            cmat[c * NBK + t] = run;
            run += v;
        }
    }
    s[t] = (t < NBK) ? run : 0;
    const int own = s[t];
    __syncthreads();
    #pragma unroll
    for (int off = 1; off < 256; off <<= 1) {
        int u = (t >= off) ? s[t - off] : 0;
        __syncthreads();
        s[t] += u;
        __syncthreads();
    }
    if (t < NBK) bstart[t] = s[t] - own;
    if (t == NBK - 1) bstart[NBK] = s[t];
}

__global__ __launch_bounds__(256) void bin_kernel(
    const int* __restrict__ dst, const int* __restrict__ src,
    const float* __restrict__ ew,
    const int* __restrict__ cmat, const int* __restrict__ bstart,
    int* __restrict__ rdst, int2* __restrict__ rpair)
{
    __shared__ int gb[NBK];
    __shared__ int cnt[NBK];
    const int tid = threadIdx.x;
    for (int t = tid; t < NBK; t += 256) {
        gb[t] = cmat[blockIdx.x * NBK + t] + bstart[t];
        cnt[t] = 0;
    }
    __syncthreads();

    const int b4 = blockIdx.x * (BIN_CHUNK / 4);
    const int e4n = N_EDGES / 4;       // E % 4 == 0
    const vint4* d4p = (const vint4*)dst;
    const vint4* s4p = (const vint4*)src;
    const vfloat4* w4p = (const vfloat4*)ew;

    #pragma unroll
    for (int q = 0; q < BIN_CHUNK / 4 / 256; ++q) {
        int i4 = b4 + q * 256 + tid;
        if (i4 < e4n) {
            vint4 d4 = __builtin_nontemporal_load(d4p + i4);
            vint4 s4 = __builtin_nontemporal_load(s4p + i4);
            vfloat4 w4 = __builtin_nontemporal_load(w4p + i4);
            #pragma unroll
            for (int j = 0; j < 4; ++j) {
                const int d = j == 0 ? d4.x : j == 1 ? d4.y : j == 2 ? d4.z : d4.w;
                const int s = j == 0 ? s4.x : j == 1 ? s4.y : j == 2 ? s4.z : s4.w;
                const float w = j == 0 ? w4.x : j == 1 ? w4.y : j == 2 ? w4.z : w4.w;
                const int bk = d >> 8;
                const int r = atomicAdd(&cnt[bk], 1);
                const int pos = gb[bk] + r;
                rdst[pos] = d;
                rpair[pos] = make_int2(s, __float_as_int(w));
            }
        }
    }
}

__global__ __launch_bounds__(256) void place_kernel(
    const int* __restrict__ bstart, const int* __restrict__ rdst,
    const int2* __restrict__ rpair,
    int* __restrict__ deg, int* __restrict__ rowptr, int2* __restrict__ epair)
{
    __shared__ int ldeg[256];
    __shared__ int ls[256];
    __shared__ int lcur[256];
    const int t = threadIdx.x;
    const int b = blockIdx.x;
    const int lo = bstart[b], hi = bstart[b + 1];
    const int nbase = b << 8;

    ldeg[t] = 0;
    __syncthreads();
    for (int i = lo + t; i < hi; i += 256)
        atomicAdd(&ldeg[rdst[i] & 255], 1);
    __syncthreads();

    const int v = ldeg[t];
    ls[t] = v;
    __syncthreads();
    #pragma unroll
    for (int off = 1; off < 256; off <<= 1) {
        int u = (t >= off) ? ls[t - off] : 0;
        __syncthreads();
        ls[t] += u;
        __syncthreads();
    }
    const int excl = ls[t] - v + lo;
    const int n = nbase + t;
    if (n < N_NODES) { rowptr[n] = excl; deg[n] = v; }
    lcur[t] = excl;
    __syncthreads();

    const vint2* rpv = (const vint2*)rpair;
    for (int i = lo + t; i < hi; i += 256) {
        const int d = rdst[i];
        vint2 rp = __builtin_nontemporal_load(rpv + i);
        const int pos = atomicAdd(&lcur[d & 255], 1);
        epair[pos] = make_int2(rp.x, rp.y);
    }
}

// ---------------- layer-0 aggregation (full 64-dim output) ----------------
// one wave per node; 8 subgroups x 8 lanes; UNROLL-BY-4: 4 independent
// gather chains per lane (latency/MLP bound). w=0 zero-fill keeps the tail
// guard-free. epair read non-temporally.
__global__ __launch_bounds__(256) void aggregate_kernel(
    const int* __restrict__ rowptr, const int* __restrict__ deg,
    const int2* __restrict__ epair,
    const float* __restrict__ s_src, const float* __restrict__ s_dst,
    const unsigned short* __restrict__ hfeat16,
    float* __restrict__ outp)
{
    const int n = blockIdx.x * 4 + (threadIdx.x >> 6);
    if (n >= N_NODES) return;
    const int lane = threadIdx.x & 63;
    const int g = lane >> 3;          // subgroup (edge slot 0..7)
    const int sl = lane & 7;          // feature octet
    const int hh = sl >> 1;           // head of my features
    const float sdst = s_dst[n * 4 + hh];
    const int beg = rowptr[n];
    const int cnt = deg[n];
    const vint2* epv = (const vint2*)epair + beg;
    const vint2 zz = {0, 0};

    float den = 0.f;
    float4 a0 = make_float4(0.f, 0.f, 0.f, 0.f);
    float4 a1 = make_float4(0.f, 0.f, 0.f, 0.f);

    int i = g;
    vint2 ep0 = (i      < cnt) ? __builtin_nontemporal_load(epv + i)      : zz;
    vint2 ep1 = (i + 8  < cnt) ? __builtin_nontemporal_load(epv + i + 8)  : zz;
    vint2 ep2 = (i + 16 < cnt) ? __builtin_nontemporal_load(epv + i + 16) : zz;
    vint2 ep3 = (i + 24 < cnt) ? __builtin_nontemporal_load(epv + i + 24) : zz;
    while (i < cnt) {
        const int s0 = ep0.x, s1 = ep1.x, s2 = ep2.x, s3 = ep3.x;
        const float w0 = __int_as_float(ep0.y);
        const float w1 = __int_as_float(ep1.y);
        const float w2 = __int_as_float(ep2.y);
        const float w3 = __int_as_float(ep3.y);
        const int in2 = i + 32;
        ep0 = (in2      < cnt) ? __builtin_nontemporal_load(epv + in2)      : zz;
        ep1 = (in2 + 8  < cnt) ? __builtin_nontemporal_load(epv + in2 + 8)  : zz;
        ep2 = (in2 + 16 < cnt) ? __builtin_nontemporal_load(epv + in2 + 16) : zz;
        ep3 = (in2 + 24 < cnt) ? __builtin_nontemporal_load(epv + in2 + 24) : zz;

        const float ss0 = s_src[(size_t)s0 * 4 + hh];
        const float ss1 = s_src[(size_t)s1 * 4 + hh];
        const float ss2 = s_src[(size_t)s2 * 4 + hh];
        const float ss3 = s_src[(size_t)s3 * 4 + hh];
        const uint4 hv0 = *(const uint4*)(hfeat16 + (size_t)s0 * 64 + sl * 8);
        const uint4 hv1 = *(const uint4*)(hfeat16 + (size_t)s1 * 64 + sl * 8);
        const uint4 hv2 = *(const uint4*)(hfeat16 + (size_t)s2 * 64 + sl * 8);
        const uint4 hv3 = *(const uint4*)(hfeat16 + (size_t)s3 * 64 + sl * 8);

        float sc0 = ss0 + sdst; sc0 = fmaxf(sc0, 0.2f * sc0);
        const float p0 = __builtin_amdgcn_exp2f(sc0) * w0;
        float sc1 = ss1 + sdst; sc1 = fmaxf(sc1, 0.2f * sc1);
        const float p1 = __builtin_amdgcn_exp2f(sc1) * w1;
        float sc2 = ss2 + sdst; sc2 = fmaxf(sc2, 0.2f * sc2);
        const float p2 = __builtin_amdgcn_exp2f(sc2) * w2;
        float sc3 = ss3 + sdst; sc3 = fmaxf(sc3, 0.2f * sc3);
        const float p3 = __builtin_amdgcn_exp2f(sc3) * w3;
        den += (p0 + p1) + (p2 + p3);

        a0.x = fmaf(p0, bf_lo(hv0.x), a0.x); a0.y = fmaf(p0, bf_hi(hv0.x), a0.y);
        a0.z = fmaf(p0, bf_lo(hv0.y), a0.z); a0.w = fmaf(p0, bf_hi(hv0.y), a0.w);
        a1.x = fmaf(p0, bf_lo(hv0.z), a1.x); a1.y = fmaf(p0, bf_hi(hv0.z), a1.y);
        a1.z = fmaf(p0, bf_lo(hv0.w), a1.z); a1.w = fmaf(p0, bf_hi(hv0.w), a1.w);
        a0.x = fmaf(p1, bf_lo(hv1.x), a0.x); a0.y = fmaf(p1, bf_hi(hv1.x), a0.y);
        a0.z = fmaf(p1, bf_lo(hv1.y), a0.z); a0.w = fmaf(p1, bf_hi(hv1.y), a0.w);
        a1.x = fmaf(p1, bf_lo(hv1.z), a1.x); a1.y = fmaf(p1, bf_hi(hv1.z), a1.y);
        a1.z = fmaf(p1, bf_lo(hv1.w), a1.z); a1.w = fmaf(p1, bf_hi(hv1.w), a1.w);
        a0.x = fmaf(p2, bf_lo(hv2.x), a0.x); a0.y = fmaf(p2, bf_hi(hv2.x), a0.y);
        a0.z = fmaf(p2, bf_lo(hv2.y), a0.z); a0.w = fmaf(p2, bf_hi(hv2.y), a0.w);
        a1.x = fmaf(p2, bf_lo(hv2.z), a1.x); a1.y = fmaf(p2, bf_hi(hv2.z), a1.y);
        a1.z = fmaf(p2, bf_lo(hv2.w), a1.z); a1.w = fmaf(p2, bf_hi(hv2.w), a1.w);
        a0.x = fmaf(p3, bf_lo(hv3.x), a0.x); a0.y = fmaf(p3, bf_hi(hv3.x), a0.y);
        a0.z = fmaf(p3, bf_lo(hv3.y), a0.z); a0.w = fmaf(p3, bf_hi(hv3.y), a0.w);
        a1.x = fmaf(p3, bf_lo(hv3.z), a1.x); a1.y = fmaf(p3, bf_hi(hv3.z), a1.y);
        a1.z = fmaf(p3, bf_lo(hv3.w), a1.z); a1.w = fmaf(p3, bf_hi(hv3.w), a1.w);

        i = in2;
    }

    // merge 8 subgroups (lane bits 3,4,5)
    #pragma unroll
    for (int off = 8; off <= 32; off <<= 1) {
        den  += __shfl_xor(den, off, 64);
        a0.x += __shfl_xor(a0.x, off, 64); a0.y += __shfl_xor(a0.y, off, 64);
        a0.z += __shfl_xor(a0.z, off, 64); a0.w += __shfl_xor(a0.w, off, 64);
        a1.x += __shfl_xor(a1.x, off, 64); a1.y += __shfl_xor(a1.y, off, 64);
        a1.z += __shfl_xor(a1.z, off, 64); a1.w += __shfl_xor(a1.w, off, 64);
    }

    const float inv = 1.f / (den + 1e-16f);
    if (g == 0) {
        float4 v0, v1;
        v0.x = a0.x * inv; v0.x = v0.x > 0.f ? v0.x : expm1f(v0.x);
        v0.y = a0.y * inv; v0.y = v0.y > 0.f ? v0.y : expm1f(v0.y);
        v0.z = a0.z * inv; v0.z = v0.z > 0.f ? v0.z : expm1f(v0.z);
        v0.w = a0.w * inv; v0.w = v0.w > 0.f ? v0.w : expm1f(v0.w);
        v1.x = a1.x * inv; v1.x = v1.x > 0.f ? v1.x : expm1f(v1.x);
        v1.y = a1.y * inv; v1.y = v1.y > 0.f ? v1.y : expm1f(v1.y);
        v1.z = a1.z * inv; v1.z = v1.z > 0.f ? v1.z : expm1f(v1.z);
        v1.w = a1.w * inv; v1.w = v1.w > 0.f ? v1.w : expm1f(v1.w);
        float4* op = (float4*)(outp + (size_t)n * 64 + sl * 8);
        op[0] = v0; op[1] = v1;
    }
}

// ---------------- layer-1 head-collapsed aggregation ----------------
// out[n] = sum_h (sum_e p_eh * hw[s_e,h]) / den_h + b. Per edge only one
// float2 {s,hw} gathered from the interleaved 32B l1tab record.
// one wave per node; 16 subgroups x 4 lanes; unroll-by-2.
__global__ __launch_bounds__(256) void head_aggregate_kernel(
    const int* __restrict__ rowptr, const int* __restrict__ deg,
    const int2* __restrict__ epair,
    const float* __restrict__ l1tab, const float* __restrict__ s_dst,
    const float* __restrict__ bhead, float* __restrict__ outp)
{
    const int n = blockIdx.x * 4 + (threadIdx.x >> 6);
    if (n >= N_NODES) return;
    const int lane = threadIdx.x & 63;
    const int g = lane >> 2;          // subgroup (edge slot 0..15)
    const int h = lane & 3;           // head
    const float sdst = s_dst[n * 4 + h];
    const int beg = rowptr[n];
    const int cnt = deg[n];
    const vint2* epv = (const vint2*)epair + beg;
    const vint2 zz = {0, 0};

    float den = 0.f, num = 0.f;

    int i = g;
    vint2 ep0 = (i < cnt) ? __builtin_nontemporal_load(epv + i) : zz;
    vint2 ep1 = (i + 16 < cnt) ? __builtin_nontemporal_load(epv + i + 16) : zz;
    while (i < cnt) {
        const int s0 = ep0.x, s1 = ep1.x;
        const float w0 = __int_as_float(ep0.y);
        const float w1 = __int_as_float(ep1.y);
        const float2 rec0 = *(const float2*)(l1tab + (size_t)s0 * 8 + h * 2);
        const float2 rec1 = *(const float2*)(l1tab + (size_t)s1 * 8 + h * 2);
        vint2 en0 = (i + 32 < cnt) ? __builtin_nontemporal_load(epv + i + 32) : zz;
        vint2 en1 = (i + 48 < cnt) ? __builtin_nontemporal_load(epv + i + 48) : zz;

        float sc0 = rec0.x + sdst;
        sc0 = fmaxf(sc0, 0.2f * sc0);                    // leaky relu (log2 domain)
        const float p0 = __builtin_amdgcn_exp2f(sc0) * w0;
        float sc1 = rec1.x + sdst;
        sc1 = fmaxf(sc1, 0.2f * sc1);
        const float p1 = __builtin_amdgcn_exp2f(sc1) * w1;
        den += p0 + p1;
        num = fmaf(p0, rec0.y, num);
        num = fmaf(p1, rec1.y, num);

        ep0 = en0; ep1 = en1; i += 32;
    }

    // merge 16 subgroups (lane bits 2..5)
    #pragma unroll
    for (int off = 4; off <= 32; off <<= 1) {
        den += __shfl_xor(den, off, 64);
        num += __shfl_xor(num, off, 64);
    }

    float v = num / (den + 1e-16f);
    v += __shfl_xor(v, 1, 64);
    v += __shfl_xor(v, 2, 64);
    if (lane == 0) outp[n] = v + bhead[0];
}

extern "C" void kernel_launch(void* const* d_in, const int* in_sizes, int n_in,
                              void* d_out, int out_size, void* d_ws, size_t ws_size,
                              hipStream_t stream) {
    const float* x      = (const float*)d_in[0];
    const int*   eidx   = (const int*)d_in[1];
    const float* ew     = (const float*)d_in[2];
    const float* tim    = (const float*)d_in[3];
    const float* omega0 = (const float*)d_in[4];
    const float* phase0 = (const float*)d_in[5];
    const float* W0     = (const float*)d_in[6];
    const float* asrc0  = (const float*)d_in[7];
    const float* adst0  = (const float*)d_in[8];
    const float* omega1 = (const float*)d_in[9];
    const float* phase1 = (const float*)d_in[10];
    const float* W1     = (const float*)d_in[11];
    const float* asrc1  = (const float*)d_in[12];
    const float* adst1  = (const float*)d_in[13];
    const float* Whead  = (const float*)d_in[14];
    const float* bhead  = (const float*)d_in[15];
    float* out = (float*)d_out;

    const int* src = eidx;
    const int* dst = eidx + N_EDGES;

    float* ws = (float*)d_ws;
    unsigned short* hfeat16 = (unsigned short*)ws;   // N*64 ushorts (6.4MB)
    float* x1    = (float*)(hfeat16 + (size_t)N_NODES * 64);  // N*64 floats
    float* s_src = x1    + (size_t)N_NODES * 64;     // N*4
    float* s_dst = s_src + (size_t)N_NODES * 4;      // N*4
    int2* epair  = (int2*)(s_dst + (size_t)N_NODES * 4);   // E int2
    int* deg     = (int*)(epair + (size_t)N_EDGES);  // N
    int* rowptr  = deg + N_NODES;                    // N
    int* bstart  = rowptr + N_NODES;                 // NBK+1
    int* cmat    = bstart + NBK + 1;                 // BIN_GRID*NBK (153KB)
    float* l1tab = (float*)(cmat + BIN_GRID * NBK);  // N*8 floats (1.6MB)
    // record arrays alias dead buffers: consumed by place() before their
    // aliases are written (hfeat16 by transform<128>, x1 by aggregate).
    int*  rdst  = (int*)hfeat16;                     // E ints
    int2* rpair = (int2*)x1;                         // E int2

    const int tf_grid  = (N_NODES + 63) / 64;        // 782
    const int agg_grid = (N_NODES + 3) / 4;

    // ---- CSR build (count-matrix bucket sort; shared by both layers) ----
    count_kernel<<<BIN_GRID, 256, 0, stream>>>(dst, cmat);
    cscan_kernel<<<1, 256, 0, stream>>>(cmat, bstart);
    bin_kernel<<<BIN_GRID, 256, 0, stream>>>(dst, src, ew, cmat, bstart, rdst, rpair);
    place_kernel<<<NBK, 256, 0, stream>>>(bstart, rdst, rpair, deg, rowptr, epair);

    // ---- layer 0 ----
    transform_kernel<128, 0><<<tf_grid, 256, 0, stream>>>(
        x, tim, omega0, phase0, W0, asrc0, adst0, Whead,
        hfeat16, s_src, s_dst, l1tab);
    aggregate_kernel<<<agg_grid, 256, 0, stream>>>(
        rowptr, deg, epair, s_src, s_dst, hfeat16, x1);

    // ---- layer 1 (head-collapsed: h@Whead folded into per-node hw) ----
    transform_kernel<64, 1><<<tf_grid, 256, 0, stream>>>(
        x1, tim, omega1, phase1, W1, asrc1, adst1, Whead,
        hfeat16, s_src, s_dst, l1tab);
    head_aggregate_kernel<<<agg_grid, 256, 0, stream>>>(
        rowptr, deg, epair, l1tab, s_dst, bhead, out);
}

// Round 22
// 196.161 us; speedup vs baseline: 1.2162x; 1.0782x over previous
//
#include <hip/hip_runtime.h>
#include <hip/hip_bf16.h>
#include <math.h>

#define N_NODES 50000
#define N_EDGES 1600000
#define TE 64
#define LOG2E 1.44269504088896340736f
#define NBK 196            // dst buckets: bucket = dst >> 8 (256 nodes each)
#define BIN_CHUNK 8192
#define BIN_GRID ((N_EDGES + BIN_CHUNK - 1) / BIN_CHUNK)   // 196

typedef int vint2 __attribute__((ext_vector_type(2)));
typedef int vint4 __attribute__((ext_vector_type(4)));
typedef float vfloat4 __attribute__((ext_vector_type(4)));
typedef unsigned int uint;

__device__ __forceinline__ unsigned short f2bf(float f) {
    uint u = __float_as_uint(f);
    return (unsigned short)((u + 0x7fffu + ((u >> 16) & 1u)) >> 16);   // RNE
}
__device__ __forceinline__ float bf_lo(uint u) { return __uint_as_float(u << 16); }
__device__ __forceinline__ float bf_hi(uint u) { return __uint_as_float(u & 0xffff0000u); }

// ---------------- node transform ----------------
// h = concat(x, cos(t*omega+phase)) @ W, register-tiled GEMM.
// BN=32 nodes/block (thread tile 2 nodes x 4 cols): grid 1563 -> ~6 blocks/CU
// (vs 3 at BN=64), doubling resident waves so per-chunk barrier+staging
// latency overlaps across waves (round-19: occupancy 17%, grid-limited).
// VGPR stays ~40 (round-20 lesson: in-wave pipelining blew VGPR to 256).
// FINAL=0: h stored bf16 + s_src/s_dst. FINAL=1: only hw[n,h]=h·Whead and
// s_src needed; writes interleaved l1tab[n]={s0,hw0,...} + s_dst.
template<int IN_DIM, int FINAL>
__global__ __launch_bounds__(256) void transform_kernel(
    const float* __restrict__ xin, const float* __restrict__ tim,
    const float* __restrict__ omega, const float* __restrict__ phase,
    const float* __restrict__ W, const float* __restrict__ asrc,
    const float* __restrict__ adst, const float* __restrict__ whead,
    unsigned short* __restrict__ hfeat16,
    float* __restrict__ s_src, float* __restrict__ s_dst,
    float* __restrict__ l1tab)
{
    constexpr int K = IN_DIM + TE;
    constexpr int KC = 32;             // k-chunk
    constexpr int NCH = K / KC;
    constexpr int BN = 32;             // nodes per block
    __shared__ float aS[KC][36];       // transposed a-chunk (padded row)
    __shared__ float wS[KC][64];
    __shared__ float tS[BN];

    const int tid = threadIdx.x;
    const int base = blockIdx.x * BN;

    if (tid < BN) {
        int n = base + tid;
        tS[tid] = (n < N_NODES) ? tim[n] : 0.f;
    }

    const int ty = tid >> 4;           // node pair: nodes ty*2 .. ty*2+1
    const int tx = tid & 15;           // col slot: cols tx*4 .. tx*4+3

    float acc[2][4] = {};

    for (int ch = 0; ch < NCH; ++ch) {
        const int kg0 = ch * KC;
        __syncthreads();               // previous chunk fully consumed

        // stage W chunk: 32x64 floats = 512 float4, 2 per thread (coalesced)
        #pragma unroll
        for (int j = 0; j < 2; ++j) {
            int idx = tid + j * 256;                    // float4 index
            int kk = idx >> 4, c4 = idx & 15;
            *(float4*)&wS[kk][c4 * 4] =
                ((const float4*)(W + (size_t)(kg0 + kk) * 64))[c4];
        }

        // stage a chunk (transposed): 32 nodes x 32 k
        if (kg0 < IN_DIM) {
            // 256 float4 = 1 per thread
            int nl = tid >> 3, kq = tid & 7, kk = kq * 4;
            int n = base + nl;
            float4 v = (n < N_NODES)
                ? ((const float4*)(xin + (size_t)n * IN_DIM + kg0))[kq]
                : make_float4(0.f, 0.f, 0.f, 0.f);
            aS[kk + 0][nl] = v.x;
            aS[kk + 1][nl] = v.y;
            aS[kk + 2][nl] = v.z;
            aS[kk + 3][nl] = v.w;
        } else {
            #pragma unroll
            for (int j = 0; j < 4; ++j) {
                int idx = tid + j * 256;
                int kk = idx >> 5, nl = idx & 31;
                int kg = kg0 + kk - IN_DIM;
                aS[kk][nl] = cosf(tS[nl] * omega[kg] + phase[kg]);
            }
        }
        __syncthreads();

        #pragma unroll
        for (int k = 0; k < KC; ++k) {
            const float2 av = *(const float2*)&aS[k][ty * 2];
            const float4 wv = *(const float4*)&wS[k][tx * 4];
            acc[0][0] = fmaf(av.x, wv.x, acc[0][0]);
            acc[0][1] = fmaf(av.x, wv.y, acc[0][1]);
            acc[0][2] = fmaf(av.x, wv.z, acc[0][2]);
            acc[0][3] = fmaf(av.x, wv.w, acc[0][3]);
            acc[1][0] = fmaf(av.y, wv.x, acc[1][0]);
            acc[1][1] = fmaf(av.y, wv.y, acc[1][1]);
            acc[1][2] = fmaf(av.y, wv.z, acc[1][2]);
            acc[1][3] = fmaf(av.y, wv.w, acc[1][3]);
        }
    }

    // epilogue: per-head scores (+ hw head-dot if FINAL; else bf16 h stores)
    const float4 as = ((const float4*)asrc)[tx];
    const float4 ad = ((const float4*)adst)[tx];
    float4 wh = make_float4(0.f, 0.f, 0.f, 0.f);
    if (FINAL) wh = ((const float4*)whead)[tx];
    #pragma unroll
    for (int j = 0; j < 2; ++j) {
        const int n = base + ty * 2 + j;
        if (!FINAL && n < N_NODES) {
            ushort4 o;
            o.x = f2bf(acc[j][0]); o.y = f2bf(acc[j][1]);
            o.z = f2bf(acc[j][2]); o.w = f2bf(acc[j][3]);
            *(ushort4*)(hfeat16 + (size_t)n * 64 + tx * 4) = o;
        }
        float vs = acc[j][0] * as.x + acc[j][1] * as.y
                 + acc[j][2] * as.z + acc[j][3] * as.w;
        float vd = acc[j][0] * ad.x + acc[j][1] * ad.y
                 + acc[j][2] * ad.z + acc[j][3] * ad.w;
        float vw = 0.f;
        if (FINAL)
            vw = acc[j][0] * wh.x + acc[j][1] * wh.y
               + acc[j][2] * wh.z + acc[j][3] * wh.w;
        vs += __shfl_xor(vs, 1, 64); vs += __shfl_xor(vs, 2, 64);
        vd += __shfl_xor(vd, 1, 64); vd += __shfl_xor(vd, 2, 64);
        if (FINAL) { vw += __shfl_xor(vw, 1, 64); vw += __shfl_xor(vw, 2, 64); }
        if ((tx & 3) == 0 && n < N_NODES) {
            if (FINAL) {
                const int hh = tx >> 2;
                l1tab[(size_t)n * 8 + hh * 2]     = vs * LOG2E;
                l1tab[(size_t)n * 8 + hh * 2 + 1] = vw;
                s_dst[n * 4 + hh] = vd * LOG2E;
            } else {
                s_src[n * 4 + (tx >> 2)] = vs * LOG2E;   // exp2 domain
                s_dst[n * 4 + (tx >> 2)] = vd * LOG2E;
            }
        }
    }
}

// ---------------- CSR build: count-matrix two-level bucket sort ----------
// Bucket = dst>>8. All random writes confined to single-block windows ->
// structural write merging. cmat[chunk][bucket] counts let bin run
// single-pass with zero global atomics.

__global__ __launch_bounds__(256) void count_kernel(
    const int* __restrict__ dst, int* __restrict__ cmat)
{
    __shared__ int c[NBK];
    for (int t = threadIdx.x; t < NBK; t += 256) c[t] = 0;
    __syncthreads();
    const int b4 = blockIdx.x * (BIN_CHUNK / 4);
    const int e4n = N_EDGES / 4;       // E % 4 == 0
    const vint4* d4p = (const vint4*)dst;
    #pragma unroll
    for (int q = 0; q < BIN_CHUNK / 4 / 256; ++q) {
        int i4 = b4 + q * 256 + threadIdx.x;
        if (i4 < e4n) {
            vint4 d4 = __builtin_nontemporal_load(d4p + i4);
            atomicAdd(&c[d4.x >> 8], 1);
            atomicAdd(&c[d4.y >> 8], 1);
            atomicAdd(&c[d4.z >> 8], 1);
            atomicAdd(&c[d4.w >> 8], 1);
        }
    }
    __syncthreads();
    for (int t = threadIdx.x; t < NBK; t += 256)
        cmat[blockIdx.x * NBK + t] = c[t];
}

__global__ __launch_bounds__(256) void cscan_kernel(
    int* __restrict__ cmat, int* __restrict__ bstart)
{
    __shared__ int s[256];
    const int t = threadIdx.x;
    int run = 0;
    if (t < NBK) {
        #pragma unroll 8
        for (int c = 0; c < BIN_GRID; ++c) {
            int v = cmat[c * NBK + t];
            cmat[c * NBK + t] = run;
            run += v;
        }
    }
    s[t] = (t < NBK) ? run : 0;
    const int own = s[t];
    __syncthreads();
    #pragma unroll
    for (int off = 1; off < 256; off <<= 1) {
        int u = (t >= off) ? s[t - off] : 0;
        __syncthreads();
        s[t] += u;
        __syncthreads();
    }
    if (t < NBK) bstart[t] = s[t] - own;
    if (t == NBK - 1) bstart[NBK] = s[t];
}

__global__ __launch_bounds__(256) void bin_kernel(
    const int* __restrict__ dst, const int* __restrict__ src,
    const float* __restrict__ ew,
    const int* __restrict__ cmat, const int* __restrict__ bstart,
    int* __restrict__ rdst, int2* __restrict__ rpair)
{
    __shared__ int gb[NBK];
    __shared__ int cnt[NBK];
    const int tid = threadIdx.x;
    for (int t = tid; t < NBK; t += 256) {
        gb[t] = cmat[blockIdx.x * NBK + t] + bstart[t];
        cnt[t] = 0;
    }
    __syncthreads();

    const int b4 = blockIdx.x * (BIN_CHUNK / 4);
    const int e4n = N_EDGES / 4;       // E % 4 == 0
    const vint4* d4p = (const vint4*)dst;
    const vint4* s4p = (const vint4*)src;
    const vfloat4* w4p = (const vfloat4*)ew;

    #pragma unroll
    for (int q = 0; q < BIN_CHUNK / 4 / 256; ++q) {
        int i4 = b4 + q * 256 + tid;
        if (i4 < e4n) {
            vint4 d4 = __builtin_nontemporal_load(d4p + i4);
            vint4 s4 = __builtin_nontemporal_load(s4p + i4);
            vfloat4 w4 = __builtin_nontemporal_load(w4p + i4);
            #pragma unroll
            for (int j = 0; j < 4; ++j) {
                const int d = j == 0 ? d4.x : j == 1 ? d4.y : j == 2 ? d4.z : d4.w;
                const int s = j == 0 ? s4.x : j == 1 ? s4.y : j == 2 ? s4.z : s4.w;
                const float w = j == 0 ? w4.x : j == 1 ? w4.y : j == 2 ? w4.z : w4.w;
                const int bk = d >> 8;
                const int r = atomicAdd(&cnt[bk], 1);
                const int pos = gb[bk] + r;
                rdst[pos] = d;
                rpair[pos] = make_int2(s, __float_as_int(w));
            }
        }
    }
}

__global__ __launch_bounds__(256) void place_kernel(
    const int* __restrict__ bstart, const int* __restrict__ rdst,
    const int2* __restrict__ rpair,
    int* __restrict__ deg, int* __restrict__ rowptr, int2* __restrict__ epair)
{
    __shared__ int ldeg[256];
    __shared__ int ls[256];
    __shared__ int lcur[256];
    const int t = threadIdx.x;
    const int b = blockIdx.x;
    const int lo = bstart[b], hi = bstart[b + 1];
    const int nbase = b << 8;

    ldeg[t] = 0;
    __syncthreads();
    for (int i = lo + t; i < hi; i += 256)
        atomicAdd(&ldeg[rdst[i] & 255], 1);
    __syncthreads();

    const int v = ldeg[t];
    ls[t] = v;
    __syncthreads();
    #pragma unroll
    for (int off = 1; off < 256; off <<= 1) {
        int u = (t >= off) ? ls[t - off] : 0;
        __syncthreads();
        ls[t] += u;
        __syncthreads();
    }
    const int excl = ls[t] - v + lo;
    const int n = nbase + t;
    if (n < N_NODES) { rowptr[n] = excl; deg[n] = v; }
    lcur[t] = excl;
    __syncthreads();

    const vint2* rpv = (const vint2*)rpair;
    for (int i = lo + t; i < hi; i += 256) {
        const int d = rdst[i];
        vint2 rp = __builtin_nontemporal_load(rpv + i);
        const int pos = atomicAdd(&lcur[d & 255], 1);
        epair[pos] = make_int2(rp.x, rp.y);
    }
}

// ---------------- layer-0 aggregation (full 64-dim output) ----------------
// ROUND-19 PROVEN VERSION (41.7us, VGPR 24, occ 65%): 8 subgroups x 8 lanes,
// unroll-by-2. Round-21 measured unroll-4 at 52.5us (VGPR 40, occ 50%) --
// extra chains cost more occupancy than the MLP they buy. epair read
// non-temporally; w=0 zero-fill keeps the tail guard-free.
__global__ __launch_bounds__(256) void aggregate_kernel(
    const int* __restrict__ rowptr, const int* __restrict__ deg,
    const int2* __restrict__ epair,
    const float* __restrict__ s_src, const float* __restrict__ s_dst,
    const unsigned short* __restrict__ hfeat16,
    float* __restrict__ outp)
{
    const int n = blockIdx.x * 4 + (threadIdx.x >> 6);
    if (n >= N_NODES) return;
    const int lane = threadIdx.x & 63;
    const int g = lane >> 3;          // subgroup (edge slot 0..7)
    const int sl = lane & 7;          // feature octet
    const int hh = sl >> 1;           // head of my features
    const float sdst = s_dst[n * 4 + hh];
    const int beg = rowptr[n];
    const int cnt = deg[n];
    const vint2* epv = (const vint2*)epair + beg;
    const vint2 zz = {0, 0};

    float den = 0.f;
    float4 a0 = make_float4(0.f, 0.f, 0.f, 0.f);
    float4 a1 = make_float4(0.f, 0.f, 0.f, 0.f);

    int i = g;
    vint2 ep0 = (i < cnt) ? __builtin_nontemporal_load(epv + i) : zz;
    vint2 ep1 = (i + 8 < cnt) ? __builtin_nontemporal_load(epv + i + 8) : zz;
    while (i < cnt) {
        const int s0 = ep0.x, s1 = ep1.x;
        const float w0 = __int_as_float(ep0.y);
        const float w1 = __int_as_float(ep1.y);
        const float ss0 = s_src[(size_t)s0 * 4 + hh];
        const float ss1 = s_src[(size_t)s1 * 4 + hh];
        const uint4 hv0 = *(const uint4*)(hfeat16 + (size_t)s0 * 64 + sl * 8);
        const uint4 hv1 = *(const uint4*)(hfeat16 + (size_t)s1 * 64 + sl * 8);
        vint2 en0 = (i + 16 < cnt) ? __builtin_nontemporal_load(epv + i + 16) : zz;
        vint2 en1 = (i + 24 < cnt) ? __builtin_nontemporal_load(epv + i + 24) : zz;

        float sc0 = ss0 + sdst;
        sc0 = fmaxf(sc0, 0.2f * sc0);                    // leaky relu (log2 domain)
        const float p0 = __builtin_amdgcn_exp2f(sc0) * w0;
        float sc1 = ss1 + sdst;
        sc1 = fmaxf(sc1, 0.2f * sc1);
        const float p1 = __builtin_amdgcn_exp2f(sc1) * w1;
        den += p0 + p1;
        a0.x = fmaf(p0, bf_lo(hv0.x), a0.x); a0.y = fmaf(p0, bf_hi(hv0.x), a0.y);
        a0.z = fmaf(p0, bf_lo(hv0.y), a0.z); a0.w = fmaf(p0, bf_hi(hv0.y), a0.w);
        a1.x = fmaf(p0, bf_lo(hv0.z), a1.x); a1.y = fmaf(p0, bf_hi(hv0.z), a1.y);
        a1.z = fmaf(p0, bf_lo(hv0.w), a1.z); a1.w = fmaf(p0, bf_hi(hv0.w), a1.w);
        a0.x = fmaf(p1, bf_lo(hv1.x), a0.x); a0.y = fmaf(p1, bf_hi(hv1.x), a0.y);
        a0.z = fmaf(p1, bf_lo(hv1.y), a0.z); a0.w = fmaf(p1, bf_hi(hv1.y), a0.w);
        a1.x = fmaf(p1, bf_lo(hv1.z), a1.x); a1.y = fmaf(p1, bf_hi(hv1.z), a1.y);
        a1.z = fmaf(p1, bf_lo(hv1.w), a1.z); a1.w = fmaf(p1, bf_hi(hv1.w), a1.w);

        ep0 = en0; ep1 = en1; i += 16;
    }

    // merge 8 subgroups (lane bits 3,4,5)
    #pragma unroll
    for (int off = 8; off <= 32; off <<= 1) {
        den  += __shfl_xor(den, off, 64);
        a0.x += __shfl_xor(a0.x, off, 64); a0.y += __shfl_xor(a0.y, off, 64);
        a0.z += __shfl_xor(a0.z, off, 64); a0.w += __shfl_xor(a0.w, off, 64);
        a1.x += __shfl_xor(a1.x, off, 64); a1.y += __shfl_xor(a1.y, off, 64);
        a1.z += __shfl_xor(a1.z, off, 64); a1.w += __shfl_xor(a1.w, off, 64);
    }

    const float inv = 1.f / (den + 1e-16f);
    if (g == 0) {
        float4 v0, v1;
        v0.x = a0.x * inv; v0.x = v0.x > 0.f ? v0.x : expm1f(v0.x);
        v0.y = a0.y * inv; v0.y = v0.y > 0.f ? v0.y : expm1f(v0.y);
        v0.z = a0.z * inv; v0.z = v0.z > 0.f ? v0.z : expm1f(v0.z);
        v0.w = a0.w * inv; v0.w = v0.w > 0.f ? v0.w : expm1f(v0.w);
        v1.x = a1.x * inv; v1.x = v1.x > 0.f ? v1.x : expm1f(v1.x);
        v1.y = a1.y * inv; v1.y = v1.y > 0.f ? v1.y : expm1f(v1.y);
        v1.z = a1.z * inv; v1.z = v1.z > 0.f ? v1.z : expm1f(v1.z);
        v1.w = a1.w * inv; v1.w = v1.w > 0.f ? v1.w : expm1f(v1.w);
        float4* op = (float4*)(outp + (size_t)n * 64 + sl * 8);
        op[0] = v0; op[1] = v1;
    }
}

// ---------------- layer-1 head-collapsed aggregation ----------------
// out[n] = sum_h (sum_e p_eh * hw[s_e,h]) / den_h + b. Per edge only one
// float2 {s,hw} gathered from the interleaved 32B l1tab record.
// one wave per node; 16 subgroups x 4 lanes; unroll-by-2.
__global__ __launch_bounds__(256) void head_aggregate_kernel(
    const int* __restrict__ rowptr, const int* __restrict__ deg,
    const int2* __restrict__ epair,
    const float* __restrict__ l1tab, const float* __restrict__ s_dst,
    const float* __restrict__ bhead, float* __restrict__ outp)
{
    const int n = blockIdx.x * 4 + (threadIdx.x >> 6);
    if (n >= N_NODES) return;
    const int lane = threadIdx.x & 63;
    const int g = lane >> 2;          // subgroup (edge slot 0..15)
    const int h = lane & 3;           // head
    const float sdst = s_dst[n * 4 + h];
    const int beg = rowptr[n];
    const int cnt = deg[n];
    const vint2* epv = (const vint2*)epair + beg;
    const vint2 zz = {0, 0};

    float den = 0.f, num = 0.f;

    int i = g;
    vint2 ep0 = (i < cnt) ? __builtin_nontemporal_load(epv + i) : zz;
    vint2 ep1 = (i + 16 < cnt) ? __builtin_nontemporal_load(epv + i + 16) : zz;
    while (i < cnt) {
        const int s0 = ep0.x, s1 = ep1.x;
        const float w0 = __int_as_float(ep0.y);
        const float w1 = __int_as_float(ep1.y);
        const float2 rec0 = *(const float2*)(l1tab + (size_t)s0 * 8 + h * 2);
        const float2 rec1 = *(const float2*)(l1tab + (size_t)s1 * 8 + h * 2);
        vint2 en0 = (i + 32 < cnt) ? __builtin_nontemporal_load(epv + i + 32) : zz;
        vint2 en1 = (i + 48 < cnt) ? __builtin_nontemporal_load(epv + i + 48) : zz;

        float sc0 = rec0.x + sdst;
        sc0 = fmaxf(sc0, 0.2f * sc0);                    // leaky relu (log2 domain)
        const float p0 = __builtin_amdgcn_exp2f(sc0) * w0;
        float sc1 = rec1.x + sdst;
        sc1 = fmaxf(sc1, 0.2f * sc1);
        const float p1 = __builtin_amdgcn_exp2f(sc1) * w1;
        den += p0 + p1;
        num = fmaf(p0, rec0.y, num);
        num = fmaf(p1, rec1.y, num);

        ep0 = en0; ep1 = en1; i += 32;
    }

    // merge 16 subgroups (lane bits 2..5)
    #pragma unroll
    for (int off = 4; off <= 32; off <<= 1) {
        den += __shfl_xor(den, off, 64);
        num += __shfl_xor(num, off, 64);
    }

    float v = num / (den + 1e-16f);
    v += __shfl_xor(v, 1, 64);
    v += __shfl_xor(v, 2, 64);
    if (lane == 0) outp[n] = v + bhead[0];
}

extern "C" void kernel_launch(void* const* d_in, const int* in_sizes, int n_in,
                              void* d_out, int out_size, void* d_ws, size_t ws_size,
                              hipStream_t stream) {
    const float* x      = (const float*)d_in[0];
    const int*   eidx   = (const int*)d_in[1];
    const float* ew     = (const float*)d_in[2];
    const float* tim    = (const float*)d_in[3];
    const float* omega0 = (const float*)d_in[4];
    const float* phase0 = (const float*)d_in[5];
    const float* W0     = (const float*)d_in[6];
    const float* asrc0  = (const float*)d_in[7];
    const float* adst0  = (const float*)d_in[8];
    const float* omega1 = (const float*)d_in[9];
    const float* phase1 = (const float*)d_in[10];
    const float* W1     = (const float*)d_in[11];
    const float* asrc1  = (const float*)d_in[12];
    const float* adst1  = (const float*)d_in[13];
    const float* Whead  = (const float*)d_in[14];
    const float* bhead  = (const float*)d_in[15];
    float* out = (float*)d_out;

    const int* src = eidx;
    const int* dst = eidx + N_EDGES;

    float* ws = (float*)d_ws;
    unsigned short* hfeat16 = (unsigned short*)ws;   // N*64 ushorts (6.4MB)
    float* x1    = (float*)(hfeat16 + (size_t)N_NODES * 64);  // N*64 floats
    float* s_src = x1    + (size_t)N_NODES * 64;     // N*4
    float* s_dst = s_src + (size_t)N_NODES * 4;      // N*4
    int2* epair  = (int2*)(s_dst + (size_t)N_NODES * 4);   // E int2
    int* deg     = (int*)(epair + (size_t)N_EDGES);  // N
    int* rowptr  = deg + N_NODES;                    // N
    int* bstart  = rowptr + N_NODES;                 // NBK+1
    int* cmat    = bstart + NBK + 1;                 // BIN_GRID*NBK (153KB)
    float* l1tab = (float*)(cmat + BIN_GRID * NBK);  // N*8 floats (1.6MB)
    // record arrays alias dead buffers: consumed by place() before their
    // aliases are written (hfeat16 by transform<128>, x1 by aggregate).
    int*  rdst  = (int*)hfeat16;                     // E ints
    int2* rpair = (int2*)x1;                         // E int2

    const int tf_grid  = (N_NODES + 31) / 32;        // 1563
    const int agg_grid = (N_NODES + 3) / 4;

    // ---- CSR build (count-matrix bucket sort; shared by both layers) ----
    count_kernel<<<BIN_GRID, 256, 0, stream>>>(dst, cmat);
    cscan_kernel<<<1, 256, 0, stream>>>(cmat, bstart);
    bin_kernel<<<BIN_GRID, 256, 0, stream>>>(dst, src, ew, cmat, bstart, rdst, rpair);
    place_kernel<<<NBK, 256, 0, stream>>>(bstart, rdst, rpair, deg, rowptr, epair);

    // ---- layer 0 ----
    transform_kernel<128, 0><<<tf_grid, 256, 0, stream>>>(
        x, tim, omega0, phase0, W0, asrc0, adst0, Whead,
        hfeat16, s_src, s_dst, l1tab);
    aggregate_kernel<<<agg_grid, 256, 0, stream>>>(
        rowptr, deg, epair, s_src, s_dst, hfeat16, x1);

    // ---- layer 1 (head-collapsed: h@Whead folded into per-node hw) ----
    transform_kernel<64, 1><<<tf_grid, 256, 0, stream>>>(
        x1, tim, omega1, phase1, W1, asrc1, adst1, Whead,
        hfeat16, s_src, s_dst, l1tab);
    head_aggregate_kernel<<<agg_grid, 256, 0, stream>>>(
        rowptr, deg, epair, l1tab, s_dst, bhead, out);
}

// Round 23
// 196.031 us; speedup vs baseline: 1.2170x; 1.0007x over previous
//
#include <hip/hip_runtime.h>
#include <hip/hip_bf16.h>
#include <math.h>

#define N_NODES 50000
#define N_EDGES 1600000
#define TE 64
#define LOG2E 1.44269504088896340736f
#define NBK 196            // dst buckets: bucket = dst >> 8 (256 nodes each)
#define BIN_CHUNK 8192
#define BIN_GRID ((N_EDGES + BIN_CHUNK - 1) / BIN_CHUNK)   // 196

typedef int vint2 __attribute__((ext_vector_type(2)));
typedef int vint4 __attribute__((ext_vector_type(4)));
typedef float vfloat4 __attribute__((ext_vector_type(4)));
typedef unsigned int uint;

__device__ __forceinline__ unsigned short f2bf(float f) {
    uint u = __float_as_uint(f);
    return (unsigned short)((u + 0x7fffu + ((u >> 16) & 1u)) >> 16);   // RNE
}
__device__ __forceinline__ float bf_lo(uint u) { return __uint_as_float(u << 16); }
__device__ __forceinline__ float bf_hi(uint u) { return __uint_as_float(u & 0xffff0000u); }

// ---------------- node transform ----------------
// ROUND-22 PROVEN VERSION. h = concat(x, cos(t*omega+phase)) @ W.
// BN=32 nodes/block (thread tile 2x4): grid 1563 -> ~6 blocks/CU for
// wave-level latency overlap. FINAL=0: h stored bf16 + s_src/s_dst.
// FINAL=1: only hw[n,h]=h·Whead + s_src needed; writes l1tab + s_dst.
template<int IN_DIM, int FINAL>
__global__ __launch_bounds__(256) void transform_kernel(
    const float* __restrict__ xin, const float* __restrict__ tim,
    const float* __restrict__ omega, const float* __restrict__ phase,
    const float* __restrict__ W, const float* __restrict__ asrc,
    const float* __restrict__ adst, const float* __restrict__ whead,
    unsigned short* __restrict__ hfeat16,
    float* __restrict__ s_src, float* __restrict__ s_dst,
    float* __restrict__ l1tab)
{
    constexpr int K = IN_DIM + TE;
    constexpr int KC = 32;             // k-chunk
    constexpr int NCH = K / KC;
    constexpr int BN = 32;             // nodes per block
    __shared__ float aS[KC][36];       // transposed a-chunk (padded row)
    __shared__ float wS[KC][64];
    __shared__ float tS[BN];

    const int tid = threadIdx.x;
    const int base = blockIdx.x * BN;

    if (tid < BN) {
        int n = base + tid;
        tS[tid] = (n < N_NODES) ? tim[n] : 0.f;
    }

    const int ty = tid >> 4;           // node pair: nodes ty*2 .. ty*2+1
    const int tx = tid & 15;           // col slot: cols tx*4 .. tx*4+3

    float acc[2][4] = {};

    for (int ch = 0; ch < NCH; ++ch) {
        const int kg0 = ch * KC;
        __syncthreads();               // previous chunk fully consumed

        // stage W chunk: 32x64 floats = 512 float4, 2 per thread (coalesced)
        #pragma unroll
        for (int j = 0; j < 2; ++j) {
            int idx = tid + j * 256;                    // float4 index
            int kk = idx >> 4, c4 = idx & 15;
            *(float4*)&wS[kk][c4 * 4] =
                ((const float4*)(W + (size_t)(kg0 + kk) * 64))[c4];
        }

        // stage a chunk (transposed): 32 nodes x 32 k
        if (kg0 < IN_DIM) {
            // 256 float4 = 1 per thread
            int nl = tid >> 3, kq = tid & 7, kk = kq * 4;
            int n = base + nl;
            float4 v = (n < N_NODES)
                ? ((const float4*)(xin + (size_t)n * IN_DIM + kg0))[kq]
                : make_float4(0.f, 0.f, 0.f, 0.f);
            aS[kk + 0][nl] = v.x;
            aS[kk + 1][nl] = v.y;
            aS[kk + 2][nl] = v.z;
            aS[kk + 3][nl] = v.w;
        } else {
            #pragma unroll
            for (int j = 0; j < 4; ++j) {
                int idx = tid + j * 256;
                int kk = idx >> 5, nl = idx & 31;
                int kg = kg0 + kk - IN_DIM;
                aS[kk][nl] = cosf(tS[nl] * omega[kg] + phase[kg]);
            }
        }
        __syncthreads();

        #pragma unroll
        for (int k = 0; k < KC; ++k) {
            const float2 av = *(const float2*)&aS[k][ty * 2];
            const float4 wv = *(const float4*)&wS[k][tx * 4];
            acc[0][0] = fmaf(av.x, wv.x, acc[0][0]);
            acc[0][1] = fmaf(av.x, wv.y, acc[0][1]);
            acc[0][2] = fmaf(av.x, wv.z, acc[0][2]);
            acc[0][3] = fmaf(av.x, wv.w, acc[0][3]);
            acc[1][0] = fmaf(av.y, wv.x, acc[1][0]);
            acc[1][1] = fmaf(av.y, wv.y, acc[1][1]);
            acc[1][2] = fmaf(av.y, wv.z, acc[1][2]);
            acc[1][3] = fmaf(av.y, wv.w, acc[1][3]);
        }
    }

    // epilogue: per-head scores (+ hw head-dot if FINAL; else bf16 h stores)
    const float4 as = ((const float4*)asrc)[tx];
    const float4 ad = ((const float4*)adst)[tx];
    float4 wh = make_float4(0.f, 0.f, 0.f, 0.f);
    if (FINAL) wh = ((const float4*)whead)[tx];
    #pragma unroll
    for (int j = 0; j < 2; ++j) {
        const int n = base + ty * 2 + j;
        if (!FINAL && n < N_NODES) {
            ushort4 o;
            o.x = f2bf(acc[j][0]); o.y = f2bf(acc[j][1]);
            o.z = f2bf(acc[j][2]); o.w = f2bf(acc[j][3]);
            *(ushort4*)(hfeat16 + (size_t)n * 64 + tx * 4) = o;
        }
        float vs = acc[j][0] * as.x + acc[j][1] * as.y
                 + acc[j][2] * as.z + acc[j][3] * as.w;
        float vd = acc[j][0] * ad.x + acc[j][1] * ad.y
                 + acc[j][2] * ad.z + acc[j][3] * ad.w;
        float vw = 0.f;
        if (FINAL)
            vw = acc[j][0] * wh.x + acc[j][1] * wh.y
               + acc[j][2] * wh.z + acc[j][3] * wh.w;
        vs += __shfl_xor(vs, 1, 64); vs += __shfl_xor(vs, 2, 64);
        vd += __shfl_xor(vd, 1, 64); vd += __shfl_xor(vd, 2, 64);
        if (FINAL) { vw += __shfl_xor(vw, 1, 64); vw += __shfl_xor(vw, 2, 64); }
        if ((tx & 3) == 0 && n < N_NODES) {
            if (FINAL) {
                const int hh = tx >> 2;
                l1tab[(size_t)n * 8 + hh * 2]     = vs * LOG2E;
                l1tab[(size_t)n * 8 + hh * 2 + 1] = vw;
                s_dst[n * 4 + hh] = vd * LOG2E;
            } else {
                s_src[n * 4 + (tx >> 2)] = vs * LOG2E;   // exp2 domain
                s_dst[n * 4 + (tx >> 2)] = vd * LOG2E;
            }
        }
    }
}

// ---------------- CSR build: count-matrix two-level bucket sort ----------
// Bucket = dst>>8. All random writes confined to single-block windows ->
// structural write merging. cmat[chunk][bucket] counts let bin run
// single-pass with zero global atomics.

__global__ __launch_bounds__(256) void count_kernel(
    const int* __restrict__ dst, int* __restrict__ cmat)
{
    __shared__ int c[NBK];
    for (int t = threadIdx.x; t < NBK; t += 256) c[t] = 0;
    __syncthreads();
    const int b4 = blockIdx.x * (BIN_CHUNK / 4);
    const int e4n = N_EDGES / 4;       // E % 4 == 0
    const vint4* d4p = (const vint4*)dst;
    #pragma unroll
    for (int q = 0; q < BIN_CHUNK / 4 / 256; ++q) {
        int i4 = b4 + q * 256 + threadIdx.x;
        if (i4 < e4n) {
            vint4 d4 = __builtin_nontemporal_load(d4p + i4);
            atomicAdd(&c[d4.x >> 8], 1);
            atomicAdd(&c[d4.y >> 8], 1);
            atomicAdd(&c[d4.z >> 8], 1);
            atomicAdd(&c[d4.w >> 8], 1);
        }
    }
    __syncthreads();
    for (int t = threadIdx.x; t < NBK; t += 256)
        cmat[blockIdx.x * NBK + t] = c[t];
}

__global__ __launch_bounds__(256) void cscan_kernel(
    int* __restrict__ cmat, int* __restrict__ bstart)
{
    __shared__ int s[256];
    const int t = threadIdx.x;
    int run = 0;
    if (t < NBK) {
        #pragma unroll 8
        for (int c = 0; c < BIN_GRID; ++c) {
            int v = cmat[c * NBK + t];
            cmat[c * NBK + t] = run;
            run += v;
        }
    }
    s[t] = (t < NBK) ? run : 0;
    const int own = s[t];
    __syncthreads();
    #pragma unroll
    for (int off = 1; off < 256; off <<= 1) {
        int u = (t >= off) ? s[t - off] : 0;
        __syncthreads();
        s[t] += u;
        __syncthreads();
    }
    if (t < NBK) bstart[t] = s[t] - own;
    if (t == NBK - 1) bstart[NBK] = s[t];
}

__global__ __launch_bounds__(256) void bin_kernel(
    const int* __restrict__ dst, const int* __restrict__ src,
    const float* __restrict__ ew,
    const int* __restrict__ cmat, const int* __restrict__ bstart,
    int* __restrict__ rdst, int2* __restrict__ rpair)
{
    __shared__ int gb[NBK];
    __shared__ int cnt[NBK];
    const int tid = threadIdx.x;
    for (int t = tid; t < NBK; t += 256) {
        gb[t] = cmat[blockIdx.x * NBK + t] + bstart[t];
        cnt[t] = 0;
    }
    __syncthreads();

    const int b4 = blockIdx.x * (BIN_CHUNK / 4);
    const int e4n = N_EDGES / 4;       // E % 4 == 0
    const vint4* d4p = (const vint4*)dst;
    const vint4* s4p = (const vint4*)src;
    const vfloat4* w4p = (const vfloat4*)ew;

    #pragma unroll
    for (int q = 0; q < BIN_CHUNK / 4 / 256; ++q) {
        int i4 = b4 + q * 256 + tid;
        if (i4 < e4n) {
            vint4 d4 = __builtin_nontemporal_load(d4p + i4);
            vint4 s4 = __builtin_nontemporal_load(s4p + i4);
            vfloat4 w4 = __builtin_nontemporal_load(w4p + i4);
            #pragma unroll
            for (int j = 0; j < 4; ++j) {
                const int d = j == 0 ? d4.x : j == 1 ? d4.y : j == 2 ? d4.z : d4.w;
                const int s = j == 0 ? s4.x : j == 1 ? s4.y : j == 2 ? s4.z : s4.w;
                const float w = j == 0 ? w4.x : j == 1 ? w4.y : j == 2 ? w4.z : w4.w;
                const int bk = d >> 8;
                const int r = atomicAdd(&cnt[bk], 1);
                const int pos = gb[bk] + r;
                rdst[pos] = d;
                rpair[pos] = make_int2(s, __float_as_int(w));
            }
        }
    }
}

__global__ __launch_bounds__(256) void place_kernel(
    const int* __restrict__ bstart, const int* __restrict__ rdst,
    const int2* __restrict__ rpair,
    int* __restrict__ deg, int* __restrict__ rowptr, int2* __restrict__ epair)
{
    __shared__ int ldeg[256];
    __shared__ int ls[256];
    __shared__ int lcur[256];
    const int t = threadIdx.x;
    const int b = blockIdx.x;
    const int lo = bstart[b], hi = bstart[b + 1];
    const int nbase = b << 8;

    ldeg[t] = 0;
    __syncthreads();
    for (int i = lo + t; i < hi; i += 256)
        atomicAdd(&ldeg[rdst[i] & 255], 1);
    __syncthreads();

    const int v = ldeg[t];
    ls[t] = v;
    __syncthreads();
    #pragma unroll
    for (int off = 1; off < 256; off <<= 1) {
        int u = (t >= off) ? ls[t - off] : 0;
        __syncthreads();
        ls[t] += u;
        __syncthreads();
    }
    const int excl = ls[t] - v + lo;
    const int n = nbase + t;
    if (n < N_NODES) { rowptr[n] = excl; deg[n] = v; }
    lcur[t] = excl;
    __syncthreads();

    const vint2* rpv = (const vint2*)rpair;
    for (int i = lo + t; i < hi; i += 256) {
        const int d = rdst[i];
        vint2 rp = __builtin_nontemporal_load(rpv + i);
        const int pos = atomicAdd(&lcur[d & 255], 1);
        epair[pos] = make_int2(rp.x, rp.y);
    }
}

// ---------------- layer-0 aggregation (full 64-dim output) ----------------
// 8 subgroups x 8 lanes, unroll-by-2 (proven best chain count) + DEPTH-2
// register-rotation pipeline: {ss,hv} for step i are preloaded while step
// i+1's {ss,hv} and step i+2's epair are issued -> 2x outstanding gathers
// per wave at +~14 VGPR (stays in the 8-waves/SIMD tier, unlike unroll-4's
// 52.5us regression). w=0 zero-fill keeps the tail guard-free (s=0 rows
// read harmlessly). epair read non-temporally.
__global__ __launch_bounds__(256) void aggregate_kernel(
    const int* __restrict__ rowptr, const int* __restrict__ deg,
    const int2* __restrict__ epair,
    const float* __restrict__ s_src, const float* __restrict__ s_dst,
    const unsigned short* __restrict__ hfeat16,
    float* __restrict__ outp)
{
    const int n = blockIdx.x * 4 + (threadIdx.x >> 6);
    if (n >= N_NODES) return;
    const int lane = threadIdx.x & 63;
    const int g = lane >> 3;          // subgroup (edge slot 0..7)
    const int sl = lane & 7;          // feature octet
    const int hh = sl >> 1;           // head of my features
    const float sdst = s_dst[n * 4 + hh];
    const int beg = rowptr[n];
    const int cnt = deg[n];
    const vint2* epv = (const vint2*)epair + beg;
    const vint2 zz = {0, 0};

    float den = 0.f;
    float4 a0 = make_float4(0.f, 0.f, 0.f, 0.f);
    float4 a1 = make_float4(0.f, 0.f, 0.f, 0.f);

    int i = g;
    // stage 0: epair + ss/hv for step 0; epair for step 1
    vint2 ep0 = (i < cnt) ? __builtin_nontemporal_load(epv + i) : zz;
    vint2 ep1 = (i + 8 < cnt) ? __builtin_nontemporal_load(epv + i + 8) : zz;
    float ss0 = s_src[(size_t)ep0.x * 4 + hh];
    float ss1 = s_src[(size_t)ep1.x * 4 + hh];
    uint4 hv0 = *(const uint4*)(hfeat16 + (size_t)ep0.x * 64 + sl * 8);
    uint4 hv1 = *(const uint4*)(hfeat16 + (size_t)ep1.x * 64 + sl * 8);
    vint2 en0 = (i + 16 < cnt) ? __builtin_nontemporal_load(epv + i + 16) : zz;
    vint2 en1 = (i + 24 < cnt) ? __builtin_nontemporal_load(epv + i + 24) : zz;

    while (i < cnt) {
        // issue step i+1's ss/hv (from en) and step i+2's epair
        const float ssn0 = s_src[(size_t)en0.x * 4 + hh];
        const float ssn1 = s_src[(size_t)en1.x * 4 + hh];
        const uint4 hvn0 = *(const uint4*)(hfeat16 + (size_t)en0.x * 64 + sl * 8);
        const uint4 hvn1 = *(const uint4*)(hfeat16 + (size_t)en1.x * 64 + sl * 8);
        vint2 enn0 = (i + 32 < cnt) ? __builtin_nontemporal_load(epv + i + 32) : zz;
        vint2 enn1 = (i + 40 < cnt) ? __builtin_nontemporal_load(epv + i + 40) : zz;

        // compute step i from preloaded registers
        const float w0 = __int_as_float(ep0.y);
        const float w1 = __int_as_float(ep1.y);
        float sc0 = ss0 + sdst;
        sc0 = fmaxf(sc0, 0.2f * sc0);                    // leaky relu (log2 domain)
        const float p0 = __builtin_amdgcn_exp2f(sc0) * w0;
        float sc1 = ss1 + sdst;
        sc1 = fmaxf(sc1, 0.2f * sc1);
        const float p1 = __builtin_amdgcn_exp2f(sc1) * w1;
        den += p0 + p1;
        a0.x = fmaf(p0, bf_lo(hv0.x), a0.x); a0.y = fmaf(p0, bf_hi(hv0.x), a0.y);
        a0.z = fmaf(p0, bf_lo(hv0.y), a0.z); a0.w = fmaf(p0, bf_hi(hv0.y), a0.w);
        a1.x = fmaf(p0, bf_lo(hv0.z), a1.x); a1.y = fmaf(p0, bf_hi(hv0.z), a1.y);
        a1.z = fmaf(p0, bf_lo(hv0.w), a1.z); a1.w = fmaf(p0, bf_hi(hv0.w), a1.w);
        a0.x = fmaf(p1, bf_lo(hv1.x), a0.x); a0.y = fmaf(p1, bf_hi(hv1.x), a0.y);
        a0.z = fmaf(p1, bf_lo(hv1.y), a0.z); a0.w = fmaf(p1, bf_hi(hv1.y), a0.w);
        a1.x = fmaf(p1, bf_lo(hv1.z), a1.x); a1.y = fmaf(p1, bf_hi(hv1.z), a1.y);
        a1.z = fmaf(p1, bf_lo(hv1.w), a1.z); a1.w = fmaf(p1, bf_hi(hv1.w), a1.w);

        // rotate
        ep0 = en0; ep1 = en1; en0 = enn0; en1 = enn1;
        ss0 = ssn0; ss1 = ssn1; hv0 = hvn0; hv1 = hvn1;
        i += 16;
    }

    // merge 8 subgroups (lane bits 3,4,5)
    #pragma unroll
    for (int off = 8; off <= 32; off <<= 1) {
        den  += __shfl_xor(den, off, 64);
        a0.x += __shfl_xor(a0.x, off, 64); a0.y += __shfl_xor(a0.y, off, 64);
        a0.z += __shfl_xor(a0.z, off, 64); a0.w += __shfl_xor(a0.w, off, 64);
        a1.x += __shfl_xor(a1.x, off, 64); a1.y += __shfl_xor(a1.y, off, 64);
        a1.z += __shfl_xor(a1.z, off, 64); a1.w += __shfl_xor(a1.w, off, 64);
    }

    const float inv = 1.f / (den + 1e-16f);
    if (g == 0) {
        float4 v0, v1;
        v0.x = a0.x * inv; v0.x = v0.x > 0.f ? v0.x : expm1f(v0.x);
        v0.y = a0.y * inv; v0.y = v0.y > 0.f ? v0.y : expm1f(v0.y);
        v0.z = a0.z * inv; v0.z = v0.z > 0.f ? v0.z : expm1f(v0.z);
        v0.w = a0.w * inv; v0.w = v0.w > 0.f ? v0.w : expm1f(v0.w);
        v1.x = a1.x * inv; v1.x = v1.x > 0.f ? v1.x : expm1f(v1.x);
        v1.y = a1.y * inv; v1.y = v1.y > 0.f ? v1.y : expm1f(v1.y);
        v1.z = a1.z * inv; v1.z = v1.z > 0.f ? v1.z : expm1f(v1.z);
        v1.w = a1.w * inv; v1.w = v1.w > 0.f ? v1.w : expm1f(v1.w);
        float4* op = (float4*)(outp + (size_t)n * 64 + sl * 8);
        op[0] = v0; op[1] = v1;
    }
}

// ---------------- layer-1 head-collapsed aggregation ----------------
// out[n] = sum_h (sum_e p_eh * hw[s_e,h]) / den_h + b. Per edge only one
// float2 {s,hw} gathered from the interleaved 32B l1tab record.
// one wave per node; 16 subgroups x 4 lanes; unroll-by-2.
__global__ __launch_bounds__(256) void head_aggregate_kernel(
    const int* __restrict__ rowptr, const int* __restrict__ deg,
    const int2* __restrict__ epair,
    const float* __restrict__ l1tab, const float* __restrict__ s_dst,
    const float* __restrict__ bhead, float* __restrict__ outp)
{
    const int n = blockIdx.x * 4 + (threadIdx.x >> 6);
    if (n >= N_NODES) return;
    const int lane = threadIdx.x & 63;
    const int g = lane >> 2;          // subgroup (edge slot 0..15)
    const int h = lane & 3;           // head
    const float sdst = s_dst[n * 4 + h];
    const int beg = rowptr[n];
    const int cnt = deg[n];
    const vint2* epv = (const vint2*)epair + beg;
    const vint2 zz = {0, 0};

    float den = 0.f, num = 0.f;

    int i = g;
    vint2 ep0 = (i < cnt) ? __builtin_nontemporal_load(epv + i) : zz;
    vint2 ep1 = (i + 16 < cnt) ? __builtin_nontemporal_load(epv + i + 16) : zz;
    while (i < cnt) {
        const int s0 = ep0.x, s1 = ep1.x;
        const float w0 = __int_as_float(ep0.y);
        const float w1 = __int_as_float(ep1.y);
        const float2 rec0 = *(const float2*)(l1tab + (size_t)s0 * 8 + h * 2);
        const float2 rec1 = *(const float2*)(l1tab + (size_t)s1 * 8 + h * 2);
        vint2 en0 = (i + 32 < cnt) ? __builtin_nontemporal_load(epv + i + 32) : zz;
        vint2 en1 = (i + 48 < cnt) ? __builtin_nontemporal_load(epv + i + 48) : zz;

        float sc0 = rec0.x + sdst;
        sc0 = fmaxf(sc0, 0.2f * sc0);                    // leaky relu (log2 domain)
        const float p0 = __builtin_amdgcn_exp2f(sc0) * w0;
        float sc1 = rec1.x + sdst;
        sc1 = fmaxf(sc1, 0.2f * sc1);
        const float p1 = __builtin_amdgcn_exp2f(sc1) * w1;
        den += p0 + p1;
        num = fmaf(p0, rec0.y, num);
        num = fmaf(p1, rec1.y, num);

        ep0 = en0; ep1 = en1; i += 32;
    }

    // merge 16 subgroups (lane bits 2..5)
    #pragma unroll
    for (int off = 4; off <= 32; off <<= 1) {
        den += __shfl_xor(den, off, 64);
        num += __shfl_xor(num, off, 64);
    }

    float v = num / (den + 1e-16f);
    v += __shfl_xor(v, 1, 64);
    v += __shfl_xor(v, 2, 64);
    if (lane == 0) outp[n] = v + bhead[0];
}

extern "C" void kernel_launch(void* const* d_in, const int* in_sizes, int n_in,
                              void* d_out, int out_size, void* d_ws, size_t ws_size,
                              hipStream_t stream) {
    const float* x      = (const float*)d_in[0];
    const int*   eidx   = (const int*)d_in[1];
    const float* ew     = (const float*)d_in[2];
    const float* tim    = (const float*)d_in[3];
    const float* omega0 = (const float*)d_in[4];
    const float* phase0 = (const float*)d_in[5];
    const float* W0     = (const float*)d_in[6];
    const float* asrc0  = (const float*)d_in[7];
    const float* adst0  = (const float*)d_in[8];
    const float* omega1 = (const float*)d_in[9];
    const float* phase1 = (const float*)d_in[10];
    const float* W1     = (const float*)d_in[11];
    const float* asrc1  = (const float*)d_in[12];
    const float* adst1  = (const float*)d_in[13];
    const float* Whead  = (const float*)d_in[14];
    const float* bhead  = (const float*)d_in[15];
    float* out = (float*)d_out;

    const int* src = eidx;
    const int* dst = eidx + N_EDGES;

    float* ws = (float*)d_ws;
    unsigned short* hfeat16 = (unsigned short*)ws;   // N*64 ushorts (6.4MB)
    float* x1    = (float*)(hfeat16 + (size_t)N_NODES * 64);  // N*64 floats
    float* s_src = x1    + (size_t)N_NODES * 64;     // N*4
    float* s_dst = s_src + (size_t)N_NODES * 4;      // N*4
    int2* epair  = (int2*)(s_dst + (size_t)N_NODES * 4);   // E int2
    int* deg     = (int*)(epair + (size_t)N_EDGES);  // N
    int* rowptr  = deg + N_NODES;                    // N
    int* bstart  = rowptr + N_NODES;                 // NBK+1
    int* cmat    = bstart + NBK + 1;                 // BIN_GRID*NBK (153KB)
    float* l1tab = (float*)(cmat + BIN_GRID * NBK);  // N*8 floats (1.6MB)
    // record arrays alias dead buffers: consumed by place() before their
    // aliases are written (hfeat16 by transform<128>, x1 by aggregate).
    int*  rdst  = (int*)hfeat16;                     // E ints
    int2* rpair = (int2*)x1;                         // E int2

    const int tf_grid  = (N_NODES + 31) / 32;        // 1563
    const int agg_grid = (N_NODES + 3) / 4;

    // ---- CSR build (count-matrix bucket sort; shared by both layers) ----
    count_kernel<<<BIN_GRID, 256, 0, stream>>>(dst, cmat);
    cscan_kernel<<<1, 256, 0, stream>>>(cmat, bstart);
    bin_kernel<<<BIN_GRID, 256, 0, stream>>>(dst, src, ew, cmat, bstart, rdst, rpair);
    place_kernel<<<NBK, 256, 0, stream>>>(bstart, rdst, rpair, deg, rowptr, epair);

    // ---- layer 0 ----
    transform_kernel<128, 0><<<tf_grid, 256, 0, stream>>>(
        x, tim, omega0, phase0, W0, asrc0, adst0, Whead,
        hfeat16, s_src, s_dst, l1tab);
    aggregate_kernel<<<agg_grid, 256, 0, stream>>>(
        rowptr, deg, epair, s_src, s_dst, hfeat16, x1);

    // ---- layer 1 (head-collapsed: h@Whead folded into per-node hw) ----
    transform_kernel<64, 1><<<tf_grid, 256, 0, stream>>>(
        x1, tim, omega1, phase1, W1, asrc1, adst1, Whead,
        hfeat16, s_src, s_dst, l1tab);
    head_aggregate_kernel<<<agg_grid, 256, 0, stream>>>(
        rowptr, deg, epair, l1tab, s_dst, bhead, out);
}